// Round 1
// baseline (879.729 us; speedup 1.0000x reference)
//
#include <hip/hip_runtime.h>
#include <math.h>
#include <stdint.h>

static constexpr int NN = 50000;   // nodes
static constexpr int NE = 800000;  // edges
static constexpr int NG = 512;     // graphs
static constexpr float BNEPS = 1e-5f;

// ---------------- CSR build ----------------

__global__ void degree_kernel(const int* __restrict__ dst, int* __restrict__ deg) {
    int e = blockIdx.x * blockDim.x + threadIdx.x;
    if (e < NE) atomicAdd(&deg[dst[e]], 1);
}

__global__ __launch_bounds__(1024) void scan_kernel(const int* __restrict__ deg,
                                                    int* __restrict__ row_ptr) {
    __shared__ int part[1024];
    int t = threadIdx.x;
    constexpr int CH = (NN + 1023) / 1024;  // 49
    int beg = t * CH;
    int end = beg + CH; if (end > NN) end = NN;
    int s = 0;
    for (int i = beg; i < end; ++i) s += deg[i];
    part[t] = s;
    __syncthreads();
    for (int off = 1; off < 1024; off <<= 1) {
        int v = (t >= off) ? part[t - off] : 0;
        __syncthreads();
        part[t] += v;
        __syncthreads();
    }
    int run = part[t] - s;  // exclusive prefix
    for (int i = beg; i < end; ++i) { row_ptr[i] = run; run += deg[i]; }
    if (t == 1023) row_ptr[NN] = part[1023];
}

__global__ void fill_kernel(const int* __restrict__ src, const int* __restrict__ dst,
                            const int* __restrict__ row_ptr, int* __restrict__ cursor,
                            int* __restrict__ cols) {
    int e = blockIdx.x * blockDim.x + threadIdx.x;
    if (e < NE) {
        int d = dst[e];
        int pos = atomicAdd(&cursor[d], 1);
        cols[row_ptr[d] + pos] = src[e];
    }
}

// ---------------- gather: agg[n] = in[n] + sum_{j->n} in[j] ----------------
// one wave (64 lanes) per node

template <int D>
__global__ void gather_kernel(const float* __restrict__ in, const int* __restrict__ row_ptr,
                              const int* __restrict__ cols, float* __restrict__ agg) {
    int node = blockIdx.x * (blockDim.x >> 6) + (threadIdx.x >> 6);
    int lane = threadIdx.x & 63;
    if (node >= NN) return;
    int beg = row_ptr[node], end = row_ptr[node + 1];
    if constexpr (D == 64) {
        float acc = in[(size_t)node * 64 + lane];
        for (int i = beg; i < end; ++i)
            acc += in[(size_t)cols[i] * 64 + lane];
        agg[(size_t)node * 64 + lane] = acc;
    } else {
        float2 acc = *(const float2*)&in[(size_t)node * 128 + lane * 2];
        for (int i = beg; i < end; ++i) {
            float2 v = *(const float2*)&in[(size_t)cols[i] * 128 + lane * 2];
            acc.x += v.x; acc.y += v.y;
        }
        *(float2*)&agg[(size_t)node * 128 + lane * 2] = acc;
    }
}

// ---------------- fused MLP: out = relu(relu(bn(In@W1+b1))@W2+b2) ----------------
// 64-row tile, 512 threads, 4x4 micro-tile per thread. K = 64 or 128.

template <int K>
__global__ __launch_bounds__(512, 1) void mlp_kernel(
    const float* __restrict__ In,   // [NN][K], aggregate incl. self
    const float* __restrict__ w1, const float* __restrict__ b1,
    const float* __restrict__ g, const float* __restrict__ be,
    const float* __restrict__ m, const float* __restrict__ v,
    const float* __restrict__ w2, const float* __restrict__ b2,
    float* __restrict__ out)        // [NN][128]
{
    constexpr int PAD = 4;
    __shared__ float sIn[64][K + PAD];
    __shared__ float sW[128][128];          // W1 (first K rows) then W2
    __shared__ float sT[64][128 + PAD];

    int tid = threadIdx.x;
    int cg = tid & 31, rg = tid >> 5;   // 32 col-groups x 16 row-groups
    int c0 = cg * 4, r0 = rg * 4;
    int rowbase = blockIdx.x * 64;

    // stage In tile
    constexpr int K4 = K / 4;
    for (int idx = tid; idx < 64 * K4; idx += 512) {
        int r = idx / K4, k4 = idx % K4;
        int n = rowbase + r;
        float4 val = make_float4(0.f, 0.f, 0.f, 0.f);
        if (n < NN) val = *(const float4*)&In[(size_t)n * K + k4 * 4];
        *(float4*)&sIn[r][k4 * 4] = val;
    }
    // stage W1
    for (int idx = tid; idx < K * 32; idx += 512) {
        int r = idx >> 5, c4 = idx & 31;
        *(float4*)&sW[r][c4 * 4] = *(const float4*)&w1[r * 128 + c4 * 4];
    }
    __syncthreads();

    // phase 1: T = bn_relu(In @ W1 + b1)
    float acc[4][4] = {};
    for (int k = 0; k < K; k += 4) {
        float4 a[4], b[4];
#pragma unroll
        for (int i = 0; i < 4; ++i) a[i] = *(const float4*)&sIn[r0 + i][k];
#pragma unroll
        for (int kk = 0; kk < 4; ++kk) b[kk] = *(const float4*)&sW[k + kk][c0];
        const float* af = (const float*)a;
        const float* bf = (const float*)b;
#pragma unroll
        for (int i = 0; i < 4; ++i) {
#pragma unroll
            for (int kk = 0; kk < 4; ++kk) {
                float av = af[i * 4 + kk];
                acc[i][0] += av * bf[kk * 4 + 0];
                acc[i][1] += av * bf[kk * 4 + 1];
                acc[i][2] += av * bf[kk * 4 + 2];
                acc[i][3] += av * bf[kk * 4 + 3];
            }
        }
    }
    // epilogue 1: bias + BN(eval) + relu -> sT
    {
        float sc[4], sh[4];
#pragma unroll
        for (int j = 0; j < 4; ++j) {
            int c = c0 + j;
            float s = g[c] * rsqrtf(v[c] + BNEPS);
            sc[j] = s;
            sh[j] = be[c] + (b1[c] - m[c]) * s;
        }
#pragma unroll
        for (int i = 0; i < 4; ++i) {
#pragma unroll
            for (int j = 0; j < 4; ++j) {
                float t = acc[i][j] * sc[j] + sh[j];
                sT[r0 + i][c0 + j] = fmaxf(t, 0.f);
            }
        }
    }
    __syncthreads();

    // stage W2 (overwrites sW)
    for (int idx = tid; idx < 128 * 32; idx += 512) {
        int r = idx >> 5, c4 = idx & 31;
        *(float4*)&sW[r][c4 * 4] = *(const float4*)&w2[r * 128 + c4 * 4];
    }
    __syncthreads();

    // phase 2: out = relu(T @ W2 + b2)
    float acc2[4][4] = {};
    for (int k = 0; k < 128; k += 4) {
        float4 a[4], b[4];
#pragma unroll
        for (int i = 0; i < 4; ++i) a[i] = *(const float4*)&sT[r0 + i][k];
#pragma unroll
        for (int kk = 0; kk < 4; ++kk) b[kk] = *(const float4*)&sW[k + kk][c0];
        const float* af = (const float*)a;
        const float* bf = (const float*)b;
#pragma unroll
        for (int i = 0; i < 4; ++i) {
#pragma unroll
            for (int kk = 0; kk < 4; ++kk) {
                float av = af[i * 4 + kk];
                acc2[i][0] += av * bf[kk * 4 + 0];
                acc2[i][1] += av * bf[kk * 4 + 1];
                acc2[i][2] += av * bf[kk * 4 + 2];
                acc2[i][3] += av * bf[kk * 4 + 3];
            }
        }
    }
    {
        float bb[4];
#pragma unroll
        for (int j = 0; j < 4; ++j) bb[j] = b2[c0 + j];
#pragma unroll
        for (int i = 0; i < 4; ++i) {
            int n = rowbase + r0 + i;
            if (n < NN) {
                float4 o;
                o.x = fmaxf(acc2[i][0] + bb[0], 0.f);
                o.y = fmaxf(acc2[i][1] + bb[1], 0.f);
                o.z = fmaxf(acc2[i][2] + bb[2], 0.f);
                o.w = fmaxf(acc2[i][3] + bb[3], 0.f);
                *(float4*)&out[(size_t)n * 128 + c0] = o;
            }
        }
    }
}

// ---------------- pooling: p[batch[n], co+f] += h[n][f], batch sorted ----------------

__global__ __launch_bounds__(128) void pool_kernel(const float* __restrict__ h,
                                                   const int* __restrict__ batch,
                                                   float* __restrict__ p, int col_off) {
    constexpr int NPB = 256;  // nodes per block
    int f = threadIdx.x;      // 0..127
    int n0 = blockIdx.x * NPB;
    float acc = 0.f;
    int cur = -1;
    for (int i = 0; i < NPB; ++i) {
        int n = n0 + i;
        if (n >= NN) break;
        int b = batch[n];
        if (b != cur) {
            if (cur >= 0) atomicAdd(&p[cur * 384 + col_off + f], acc);
            acc = 0.f;
            cur = b;
        }
        acc += h[(size_t)n * 128 + f];
    }
    if (cur >= 0) atomicAdd(&p[cur * 384 + col_off + f], acc);
}

// ---------------- head: relu(p@lin1+b) @ lin2 + b -> log_softmax ----------------

__global__ __launch_bounds__(384) void head_kernel(const float* __restrict__ p,
                                                   const float* __restrict__ w1,
                                                   const float* __restrict__ b1,
                                                   const float* __restrict__ w2,
                                                   const float* __restrict__ b2,
                                                   float* __restrict__ out) {
    __shared__ float sP[384];
    __shared__ float sH[384];
    __shared__ float sL[10];
    __shared__ float sred[2];
    int gidx = blockIdx.x;
    int t = threadIdx.x;
    sP[t] = p[gidx * 384 + t];
    __syncthreads();
    float acc = b1[t];
#pragma unroll 8
    for (int i = 0; i < 384; ++i) acc += sP[i] * w1[i * 384 + t];
    sH[t] = fmaxf(acc, 0.f);
    __syncthreads();
    if (t < 10) {
        float a2 = b2[t];
#pragma unroll 8
        for (int i = 0; i < 384; ++i) a2 += sH[i] * w2[i * 10 + t];
        sL[t] = a2;
    }
    __syncthreads();
    if (t == 0) {
        float mx = -1e30f;
        for (int c = 0; c < 10; ++c) mx = fmaxf(mx, sL[c]);
        float s = 0.f;
        for (int c = 0; c < 10; ++c) s += expf(sL[c] - mx);
        sred[0] = mx;
        sred[1] = logf(s);
    }
    __syncthreads();
    if (t < 10) out[gidx * 10 + t] = sL[t] - sred[0] - sred[1];
}

// ---------------- launch ----------------

static inline char* align_up(char* ptr, size_t a) {
    return (char*)(((uintptr_t)ptr + a - 1) & ~(uintptr_t)(a - 1));
}

extern "C" void kernel_launch(void* const* d_in, const int* in_sizes, int n_in,
                              void* d_out, int out_size, void* d_ws, size_t ws_size,
                              hipStream_t stream) {
    const float* x = (const float*)d_in[0];
    const int* ei = (const int*)d_in[1];
    const int* batch = (const int*)d_in[2];
    const float* c_w1[3], *c_b1[3], *c_g[3], *c_be[3], *c_m[3], *c_v[3], *c_w2[3], *c_b2[3];
    for (int i = 0; i < 3; ++i) {
        int base = 3 + i * 8;
        c_w1[i] = (const float*)d_in[base + 0];
        c_b1[i] = (const float*)d_in[base + 1];
        c_g[i]  = (const float*)d_in[base + 2];
        c_be[i] = (const float*)d_in[base + 3];
        c_m[i]  = (const float*)d_in[base + 4];
        c_v[i]  = (const float*)d_in[base + 5];
        c_w2[i] = (const float*)d_in[base + 6];
        c_b2[i] = (const float*)d_in[base + 7];
    }
    const float* lin1_w = (const float*)d_in[27];
    const float* lin1_b = (const float*)d_in[28];
    const float* lin2_w = (const float*)d_in[29];
    const float* lin2_b = (const float*)d_in[30];
    const int* src = ei;
    const int* dst = ei + NE;
    float* out = (float*)d_out;

    // workspace carve
    char* ws = (char*)d_ws;
    float* bufA = (float*)ws;  ws = align_up(ws + (size_t)NN * 128 * 4, 256);
    float* bufB = (float*)ws;  ws = align_up(ws + (size_t)NN * 128 * 4, 256);
    float* agg  = (float*)ws;  ws = align_up(ws + (size_t)NN * 128 * 4, 256);
    float* p    = (float*)ws;  ws = align_up(ws + (size_t)NG * 384 * 4, 256);
    int* csr_row = (int*)ws;   ws = align_up(ws + (size_t)(NN + 1) * 4, 256);
    int* cursor  = (int*)ws;   ws = align_up(ws + (size_t)NN * 4, 256);
    int* csr_src = (int*)ws;   ws = align_up(ws + (size_t)NE * 4, 256);

    // --- CSR build (per call; deterministic work) ---
    hipMemsetAsync(cursor, 0, (size_t)NN * 4, stream);
    degree_kernel<<<(NE + 255) / 256, 256, 0, stream>>>(dst, cursor);
    scan_kernel<<<1, 1024, 0, stream>>>(cursor, csr_row);
    hipMemsetAsync(cursor, 0, (size_t)NN * 4, stream);
    fill_kernel<<<(NE + 255) / 256, 256, 0, stream>>>(src, dst, csr_row, cursor, csr_src);
    hipMemsetAsync(p, 0, (size_t)NG * 384 * 4, stream);

    const int GATHER_BLOCKS = (NN + 3) / 4;   // 4 waves/block, one wave per node
    const int MLP_BLOCKS = (NN + 63) / 64;
    const int POOL_BLOCKS = (NN + 255) / 256;

    // layer 1: in = x (D=64)
    gather_kernel<64><<<GATHER_BLOCKS, 256, 0, stream>>>(x, csr_row, csr_src, agg);
    mlp_kernel<64><<<MLP_BLOCKS, 512, 0, stream>>>(agg, c_w1[0], c_b1[0], c_g[0], c_be[0],
                                                   c_m[0], c_v[0], c_w2[0], c_b2[0], bufA);
    pool_kernel<<<POOL_BLOCKS, 128, 0, stream>>>(bufA, batch, p, 0);

    // layer 2
    gather_kernel<128><<<GATHER_BLOCKS, 256, 0, stream>>>(bufA, csr_row, csr_src, agg);
    mlp_kernel<128><<<MLP_BLOCKS, 512, 0, stream>>>(agg, c_w1[1], c_b1[1], c_g[1], c_be[1],
                                                    c_m[1], c_v[1], c_w2[1], c_b2[1], bufB);
    pool_kernel<<<POOL_BLOCKS, 128, 0, stream>>>(bufB, batch, p, 128);

    // layer 3
    gather_kernel<128><<<GATHER_BLOCKS, 256, 0, stream>>>(bufB, csr_row, csr_src, agg);
    mlp_kernel<128><<<MLP_BLOCKS, 512, 0, stream>>>(agg, c_w1[2], c_b1[2], c_g[2], c_be[2],
                                                    c_m[2], c_v[2], c_w2[2], c_b2[2], bufA);
    pool_kernel<<<POOL_BLOCKS, 128, 0, stream>>>(bufA, batch, p, 256);

    // head
    head_kernel<<<NG, 384, 0, stream>>>(p, lin1_w, lin1_b, lin2_w, lin2_b, out);
}

// Round 2
// 608.638 us; speedup vs baseline: 1.4454x; 1.4454x over previous
//
#include <hip/hip_runtime.h>
#include <math.h>
#include <stdint.h>

static constexpr int NN = 50000;   // nodes
static constexpr int NE = 800000;  // edges
static constexpr int NG = 512;     // graphs
static constexpr float BNEPS = 1e-5f;

typedef __bf16 bf16x8 __attribute__((ext_vector_type(8)));
typedef __bf16 bf16x2 __attribute__((ext_vector_type(2)));
typedef float f32x4 __attribute__((ext_vector_type(4)));

__device__ __forceinline__ uint32_t pack_bf16(float x, float y) {
    bf16x2 v; v[0] = (__bf16)x; v[1] = (__bf16)y;
    return __builtin_bit_cast(uint32_t, v);
}
__device__ __forceinline__ float2 unpack_bf16(uint32_t u) {
    bf16x2 v = __builtin_bit_cast(bf16x2, u);
    return make_float2((float)v[0], (float)v[1]);
}

// ---------------- CSR build ----------------

__global__ void degree_kernel(const int* __restrict__ dst, int* __restrict__ deg) {
    int e = blockIdx.x * blockDim.x + threadIdx.x;
    if (e < NE) atomicAdd(&deg[dst[e]], 1);
}

__global__ __launch_bounds__(1024) void scan_kernel(const int* __restrict__ deg,
                                                    int* __restrict__ row_ptr) {
    __shared__ int part[1024];
    int t = threadIdx.x;
    constexpr int CH = (NN + 1023) / 1024;  // 49
    int beg = t * CH;
    int end = beg + CH; if (end > NN) end = NN;
    int s = 0;
    for (int i = beg; i < end; ++i) s += deg[i];
    part[t] = s;
    __syncthreads();
    for (int off = 1; off < 1024; off <<= 1) {
        int v = (t >= off) ? part[t - off] : 0;
        __syncthreads();
        part[t] += v;
        __syncthreads();
    }
    int run = part[t] - s;  // exclusive prefix
    for (int i = beg; i < end; ++i) { row_ptr[i] = run; run += deg[i]; }
    if (t == 1023) row_ptr[NN] = part[1023];
}

__global__ void fill_kernel(const int* __restrict__ src, const int* __restrict__ dst,
                            const int* __restrict__ row_ptr, int* __restrict__ cursor,
                            int* __restrict__ cols) {
    int e = blockIdx.x * blockDim.x + threadIdx.x;
    if (e < NE) {
        int d = dst[e];
        int pos = atomicAdd(&cursor[d], 1);
        cols[row_ptr[d] + pos] = src[e];
    }
}

// ---------------- prep: fp32 -> bf16 conversions ----------------

__global__ void convert_x_kernel(const float* __restrict__ x, __bf16* __restrict__ xb) {
    int i = blockIdx.x * blockDim.x + threadIdx.x;  // over NN*64/4
    if (i < NN * 16) {
        float4 v = *(const float4*)&x[i * 4];
        xb[i * 4 + 0] = (__bf16)v.x;
        xb[i * 4 + 1] = (__bf16)v.y;
        xb[i * 4 + 2] = (__bf16)v.z;
        xb[i * 4 + 3] = (__bf16)v.w;
    }
}

// w [K][128] fp32 -> wt [128][K] bf16
__global__ void transpose_w_kernel(const float* __restrict__ w, __bf16* __restrict__ wt, int K) {
    int i = blockIdx.x * blockDim.x + threadIdx.x;
    if (i < 128 * K) {
        int n = i / K, k = i % K;
        wt[i] = (__bf16)w[k * 128 + n];
    }
}

// ---------------- gather: agg[n] = in[n] + sum_{j->n} in[j]  (bf16 in/out, fp32 accum) ----------------
// one wave (64 lanes) per node

__global__ void gather64_kernel(const __bf16* __restrict__ in, const int* __restrict__ row_ptr,
                                const int* __restrict__ cols, __bf16* __restrict__ agg) {
    int node = blockIdx.x * (blockDim.x >> 6) + (threadIdx.x >> 6);
    int lane = threadIdx.x & 63;
    if (node >= NN) return;
    int beg = row_ptr[node], end = row_ptr[node + 1];
    float acc = (float)in[(size_t)node * 64 + lane];
    int i = beg;
    for (; i + 4 <= end; i += 4) {
        int c0 = cols[i], c1 = cols[i + 1], c2 = cols[i + 2], c3 = cols[i + 3];
        float v0 = (float)in[(size_t)c0 * 64 + lane];
        float v1 = (float)in[(size_t)c1 * 64 + lane];
        float v2 = (float)in[(size_t)c2 * 64 + lane];
        float v3 = (float)in[(size_t)c3 * 64 + lane];
        acc += (v0 + v1) + (v2 + v3);
    }
    for (; i < end; ++i) acc += (float)in[(size_t)cols[i] * 64 + lane];
    agg[(size_t)node * 64 + lane] = (__bf16)acc;
}

__global__ void gather128_kernel(const __bf16* __restrict__ in, const int* __restrict__ row_ptr,
                                 const int* __restrict__ cols, __bf16* __restrict__ agg) {
    int node = blockIdx.x * (blockDim.x >> 6) + (threadIdx.x >> 6);
    int lane = threadIdx.x & 63;
    if (node >= NN) return;
    const uint32_t* inu = (const uint32_t*)in;
    uint32_t* aggu = (uint32_t*)agg;
    int beg = row_ptr[node], end = row_ptr[node + 1];
    float2 acc = unpack_bf16(inu[(size_t)node * 64 + lane]);
    int i = beg;
    for (; i + 4 <= end; i += 4) {
        int c0 = cols[i], c1 = cols[i + 1], c2 = cols[i + 2], c3 = cols[i + 3];
        uint32_t u0 = inu[(size_t)c0 * 64 + lane];
        uint32_t u1 = inu[(size_t)c1 * 64 + lane];
        uint32_t u2 = inu[(size_t)c2 * 64 + lane];
        uint32_t u3 = inu[(size_t)c3 * 64 + lane];
        float2 v0 = unpack_bf16(u0), v1 = unpack_bf16(u1);
        float2 v2 = unpack_bf16(u2), v3 = unpack_bf16(u3);
        acc.x += (v0.x + v1.x) + (v2.x + v3.x);
        acc.y += (v0.y + v1.y) + (v2.y + v3.y);
    }
    for (; i < end; ++i) {
        float2 v = unpack_bf16(inu[(size_t)cols[i] * 64 + lane]);
        acc.x += v.x; acc.y += v.y;
    }
    aggu[(size_t)node * 64 + lane] = pack_bf16(acc.x, acc.y);
}

// ---------------- fused MLP via MFMA: out = relu(relu(bn(In@W1+b1))@W2+b2) ----------------
// 64 rows x 128 cols per block, 8 waves (4 row-groups x 2 col-groups),
// mfma_f32_16x16x32_bf16. Weights pre-transposed to [n][k] bf16.

template <int K>
__global__ __launch_bounds__(512, 1) void mlp_mfma_kernel(
    const __bf16* __restrict__ agg,   // [NN][K] bf16
    const __bf16* __restrict__ w1t,   // [128][K] bf16 (transposed)
    const float* __restrict__ b1,
    const float* __restrict__ g, const float* __restrict__ be,
    const float* __restrict__ m, const float* __restrict__ v,
    const __bf16* __restrict__ w2t,   // [128][128] bf16 (transposed)
    const float* __restrict__ b2,
    __bf16* __restrict__ out)         // [NN][128] bf16
{
    constexpr int KP = K + 8;     // pad 8 bf16 (16B): 2-way banks only
    constexpr int KP2 = 136;      // 128 + 8
    __shared__ alignas(16) __bf16 sA[64 * KP];
    __shared__ alignas(16) __bf16 sW1[128 * KP];
    __shared__ alignas(16) __bf16 sW2[128 * KP2];
    __shared__ alignas(16) __bf16 sT[64 * KP2];
    __shared__ alignas(16) __bf16 sOut[64 * KP2];

    int tid = threadIdx.x;
    int wid = tid >> 6, lane = tid & 63;
    int wr = wid >> 1, wc = wid & 1;       // 4 x 2 wave grid
    int l15 = lane & 15, lq = lane >> 4;   // quad 0..3
    int rowbase = blockIdx.x * 64;

    // stage In tile [64][K]
    for (int idx = tid; idx < 64 * (K / 8); idx += 512) {
        int r = idx / (K / 8), kc = idx % (K / 8);
        int n = rowbase + r;
        uint4 val = make_uint4(0, 0, 0, 0);
        if (n < NN) val = *(const uint4*)&agg[(size_t)n * K + kc * 8];
        *(uint4*)&sA[r * KP + kc * 8] = val;
    }
    // stage W1t [128][K]
    for (int idx = tid; idx < 128 * (K / 8); idx += 512) {
        int n = idx / (K / 8), kc = idx % (K / 8);
        *(uint4*)&sW1[n * KP + kc * 8] = *(const uint4*)&w1t[n * K + kc * 8];
    }
    // stage W2t [128][128]
    for (int idx = tid; idx < 128 * 16; idx += 512) {
        int n = idx >> 4, kc = idx & 15;
        *(uint4*)&sW2[n * KP2 + kc * 8] = *(const uint4*)&w2t[n * 128 + kc * 8];
    }
    __syncthreads();

    // phase 1: T = relu(bn(In @ W1 + b1))   (wave: 16 rows x 64 cols)
    f32x4 acc[4] = {};
#pragma unroll
    for (int ks = 0; ks < K / 32; ++ks) {
        bf16x8 a = *(const bf16x8*)&sA[(wr * 16 + l15) * KP + ks * 32 + lq * 8];
#pragma unroll
        for (int nf = 0; nf < 4; ++nf) {
            bf16x8 b = *(const bf16x8*)&sW1[(wc * 64 + nf * 16 + l15) * KP + ks * 32 + lq * 8];
            acc[nf] = __builtin_amdgcn_mfma_f32_16x16x32_bf16(a, b, acc[nf], 0, 0, 0);
        }
    }
    // epilogue 1: D[m][n]: n = l15, m = lq*4 + r
#pragma unroll
    for (int nf = 0; nf < 4; ++nf) {
        int c = wc * 64 + nf * 16 + l15;
        float sc = g[c] * rsqrtf(v[c] + BNEPS);
        float sh = be[c] + (b1[c] - m[c]) * sc;
#pragma unroll
        for (int r = 0; r < 4; ++r) {
            int row = wr * 16 + lq * 4 + r;
            float t = fmaxf(acc[nf][r] * sc + sh, 0.f);
            sT[row * KP2 + c] = (__bf16)t;
        }
    }
    __syncthreads();

    // phase 2: out = relu(T @ W2 + b2)
    f32x4 acc2[4] = {};
#pragma unroll
    for (int ks = 0; ks < 4; ++ks) {
        bf16x8 a = *(const bf16x8*)&sT[(wr * 16 + l15) * KP2 + ks * 32 + lq * 8];
#pragma unroll
        for (int nf = 0; nf < 4; ++nf) {
            bf16x8 b = *(const bf16x8*)&sW2[(wc * 64 + nf * 16 + l15) * KP2 + ks * 32 + lq * 8];
            acc2[nf] = __builtin_amdgcn_mfma_f32_16x16x32_bf16(a, b, acc2[nf], 0, 0, 0);
        }
    }
#pragma unroll
    for (int nf = 0; nf < 4; ++nf) {
        int c = wc * 64 + nf * 16 + l15;
        float bb = b2[c];
#pragma unroll
        for (int r = 0; r < 4; ++r) {
            int row = wr * 16 + lq * 4 + r;
            float o = fmaxf(acc2[nf][r] + bb, 0.f);
            sOut[row * KP2 + c] = (__bf16)o;
        }
    }
    __syncthreads();

    // coalesced store
    for (int idx = tid; idx < 64 * 16; idx += 512) {
        int r = idx >> 4, kc = idx & 15;
        int n = rowbase + r;
        if (n < NN)
            *(uint4*)&out[(size_t)n * 128 + kc * 8] = *(const uint4*)&sOut[r * KP2 + kc * 8];
    }
}

// ---------------- pooling: p[batch[n], co+f] += h[n][f], batch sorted ----------------

__global__ __launch_bounds__(128) void pool_kernel(const __bf16* __restrict__ h,
                                                   const int* __restrict__ batch,
                                                   float* __restrict__ p, int col_off) {
    constexpr int NPB = 256;  // nodes per block
    int f = threadIdx.x;      // 0..127
    int n0 = blockIdx.x * NPB;
    float acc = 0.f;
    int cur = -1;
    for (int i = 0; i < NPB; ++i) {
        int n = n0 + i;
        if (n >= NN) break;
        int b = batch[n];
        if (b != cur) {
            if (cur >= 0) atomicAdd(&p[cur * 384 + col_off + f], acc);
            acc = 0.f;
            cur = b;
        }
        acc += (float)h[(size_t)n * 128 + f];
    }
    if (cur >= 0) atomicAdd(&p[cur * 384 + col_off + f], acc);
}

// ---------------- head: relu(p@lin1+b) @ lin2 + b -> log_softmax ----------------

__global__ __launch_bounds__(384) void head_kernel(const float* __restrict__ p,
                                                   const float* __restrict__ w1,
                                                   const float* __restrict__ b1,
                                                   const float* __restrict__ w2,
                                                   const float* __restrict__ b2,
                                                   float* __restrict__ out) {
    __shared__ float sP[384];
    __shared__ float sH[384];
    __shared__ float sL[10];
    __shared__ float sred[2];
    int gidx = blockIdx.x;
    int t = threadIdx.x;
    sP[t] = p[gidx * 384 + t];
    __syncthreads();
    float acc = b1[t];
#pragma unroll 8
    for (int i = 0; i < 384; ++i) acc += sP[i] * w1[i * 384 + t];
    sH[t] = fmaxf(acc, 0.f);
    __syncthreads();
    if (t < 10) {
        float a2 = b2[t];
#pragma unroll 8
        for (int i = 0; i < 384; ++i) a2 += sH[i] * w2[i * 10 + t];
        sL[t] = a2;
    }
    __syncthreads();
    if (t == 0) {
        float mx = -1e30f;
        for (int c = 0; c < 10; ++c) mx = fmaxf(mx, sL[c]);
        float s = 0.f;
        for (int c = 0; c < 10; ++c) s += expf(sL[c] - mx);
        sred[0] = mx;
        sred[1] = logf(s);
    }
    __syncthreads();
    if (t < 10) out[gidx * 10 + t] = sL[t] - sred[0] - sred[1];
}

// ---------------- launch ----------------

static inline char* align_up(char* ptr, size_t a) {
    return (char*)(((uintptr_t)ptr + a - 1) & ~(uintptr_t)(a - 1));
}

extern "C" void kernel_launch(void* const* d_in, const int* in_sizes, int n_in,
                              void* d_out, int out_size, void* d_ws, size_t ws_size,
                              hipStream_t stream) {
    const float* x = (const float*)d_in[0];
    const int* ei = (const int*)d_in[1];
    const int* batch = (const int*)d_in[2];
    const float* c_w1[3], *c_b1[3], *c_g[3], *c_be[3], *c_m[3], *c_v[3], *c_w2[3], *c_b2[3];
    for (int i = 0; i < 3; ++i) {
        int base = 3 + i * 8;
        c_w1[i] = (const float*)d_in[base + 0];
        c_b1[i] = (const float*)d_in[base + 1];
        c_g[i]  = (const float*)d_in[base + 2];
        c_be[i] = (const float*)d_in[base + 3];
        c_m[i]  = (const float*)d_in[base + 4];
        c_v[i]  = (const float*)d_in[base + 5];
        c_w2[i] = (const float*)d_in[base + 6];
        c_b2[i] = (const float*)d_in[base + 7];
    }
    const float* lin1_w = (const float*)d_in[27];
    const float* lin1_b = (const float*)d_in[28];
    const float* lin2_w = (const float*)d_in[29];
    const float* lin2_b = (const float*)d_in[30];
    const int* src = ei;
    const int* dst = ei + NE;
    float* out = (float*)d_out;

    // workspace carve
    char* ws = (char*)d_ws;
    __bf16* xb  = (__bf16*)ws; ws = align_up(ws + (size_t)NN * 64 * 2, 256);
    __bf16* agg = (__bf16*)ws; ws = align_up(ws + (size_t)NN * 128 * 2, 256);
    __bf16* hA  = (__bf16*)ws; ws = align_up(ws + (size_t)NN * 128 * 2, 256);
    __bf16* hB  = (__bf16*)ws; ws = align_up(ws + (size_t)NN * 128 * 2, 256);
    float* p    = (float*)ws;  ws = align_up(ws + (size_t)NG * 384 * 4, 256);
    int* csr_row = (int*)ws;   ws = align_up(ws + (size_t)(NN + 1) * 4, 256);
    int* cursor  = (int*)ws;   ws = align_up(ws + (size_t)NN * 4, 256);
    int* csr_src = (int*)ws;   ws = align_up(ws + (size_t)NE * 4, 256);
    __bf16* w1t[3]; __bf16* w2t[3];
    for (int i = 0; i < 3; ++i) {
        int K = (i == 0) ? 64 : 128;
        w1t[i] = (__bf16*)ws; ws = align_up(ws + (size_t)128 * K * 2, 256);
        w2t[i] = (__bf16*)ws; ws = align_up(ws + (size_t)128 * 128 * 2, 256);
    }

    // --- prep: CSR build + dtype conversions (per call; deterministic) ---
    hipMemsetAsync(cursor, 0, (size_t)NN * 4, stream);
    degree_kernel<<<(NE + 255) / 256, 256, 0, stream>>>(dst, cursor);
    scan_kernel<<<1, 1024, 0, stream>>>(cursor, csr_row);
    hipMemsetAsync(cursor, 0, (size_t)NN * 4, stream);
    fill_kernel<<<(NE + 255) / 256, 256, 0, stream>>>(src, dst, csr_row, cursor, csr_src);
    hipMemsetAsync(p, 0, (size_t)NG * 384 * 4, stream);

    convert_x_kernel<<<(NN * 16 + 255) / 256, 256, 0, stream>>>(x, xb);
    for (int i = 0; i < 3; ++i) {
        int K = (i == 0) ? 64 : 128;
        transpose_w_kernel<<<(128 * K + 255) / 256, 256, 0, stream>>>(c_w1[i], w1t[i], K);
        transpose_w_kernel<<<(128 * 128 + 255) / 256, 256, 0, stream>>>(c_w2[i], w2t[i], 128);
    }

    const int GATHER_BLOCKS = (NN + 3) / 4;   // 4 waves/block, one wave per node
    const int MLP_BLOCKS = (NN + 63) / 64;
    const int POOL_BLOCKS = (NN + 255) / 256;

    // layer 1 (K=64)
    gather64_kernel<<<GATHER_BLOCKS, 256, 0, stream>>>(xb, csr_row, csr_src, agg);
    mlp_mfma_kernel<64><<<MLP_BLOCKS, 512, 0, stream>>>(agg, w1t[0], c_b1[0], c_g[0], c_be[0],
                                                        c_m[0], c_v[0], w2t[0], c_b2[0], hA);
    pool_kernel<<<POOL_BLOCKS, 128, 0, stream>>>(hA, batch, p, 0);

    // layer 2 (K=128)
    gather128_kernel<<<GATHER_BLOCKS, 256, 0, stream>>>(hA, csr_row, csr_src, agg);
    mlp_mfma_kernel<128><<<MLP_BLOCKS, 512, 0, stream>>>(agg, w1t[1], c_b1[1], c_g[1], c_be[1],
                                                         c_m[1], c_v[1], w2t[1], c_b2[1], hB);
    pool_kernel<<<POOL_BLOCKS, 128, 0, stream>>>(hB, batch, p, 128);

    // layer 3 (K=128)
    gather128_kernel<<<GATHER_BLOCKS, 256, 0, stream>>>(hB, csr_row, csr_src, agg);
    mlp_mfma_kernel<128><<<MLP_BLOCKS, 512, 0, stream>>>(agg, w1t[2], c_b1[2], c_g[2], c_be[2],
                                                         c_m[2], c_v[2], w2t[2], c_b2[2], hA);
    pool_kernel<<<POOL_BLOCKS, 128, 0, stream>>>(hA, batch, p, 256);

    // head
    head_kernel<<<NG, 384, 0, stream>>>(p, lin1_w, lin1_b, lin2_w, lin2_b, out);
}

// Round 3
// 394.796 us; speedup vs baseline: 2.2283x; 1.5417x over previous
//
#include <hip/hip_runtime.h>
#include <math.h>
#include <stdint.h>

static constexpr int NN = 50000;   // nodes
static constexpr int NE = 800000;  // edges
static constexpr int NG = 512;     // graphs
static constexpr float BNEPS = 1e-5f;

typedef __bf16 bf16x8 __attribute__((ext_vector_type(8)));
typedef __bf16 bf16x2 __attribute__((ext_vector_type(2)));
typedef float f32x4 __attribute__((ext_vector_type(4)));

__device__ __forceinline__ uint32_t pack_bf16(float x, float y) {
    bf16x2 v; v[0] = (__bf16)x; v[1] = (__bf16)y;
    return __builtin_bit_cast(uint32_t, v);
}
__device__ __forceinline__ float2 unpack_bf16(uint32_t u) {
    bf16x2 v = __builtin_bit_cast(bf16x2, u);
    return make_float2((float)v[0], (float)v[1]);
}

// ---------------- CSR build ----------------

__global__ void degree_kernel(const int* __restrict__ dst, int* __restrict__ deg) {
    int e = blockIdx.x * blockDim.x + threadIdx.x;
    if (e < NE) atomicAdd(&deg[dst[e]], 1);
}

__global__ __launch_bounds__(1024) void scan_kernel(const int* __restrict__ deg,
                                                    int* __restrict__ row_ptr) {
    __shared__ int part[1024];
    int t = threadIdx.x;
    constexpr int CH = (NN + 1023) / 1024;  // 49
    int beg = t * CH;
    int end = beg + CH; if (end > NN) end = NN;
    int s = 0;
    for (int i = beg; i < end; ++i) s += deg[i];
    part[t] = s;
    __syncthreads();
    for (int off = 1; off < 1024; off <<= 1) {
        int v = (t >= off) ? part[t - off] : 0;
        __syncthreads();
        part[t] += v;
        __syncthreads();
    }
    int run = part[t] - s;  // exclusive prefix
    for (int i = beg; i < end; ++i) { row_ptr[i] = run; run += deg[i]; }
    if (t == 1023) row_ptr[NN] = part[1023];
}

__global__ void fill_kernel(const int* __restrict__ src, const int* __restrict__ dst,
                            const int* __restrict__ row_ptr, int* __restrict__ cursor,
                            int* __restrict__ cols) {
    int e = blockIdx.x * blockDim.x + threadIdx.x;
    if (e < NE) {
        int d = dst[e];
        int pos = atomicAdd(&cursor[d], 1);
        cols[row_ptr[d] + pos] = src[e];
    }
}

// ---------------- prep: fp32 -> bf16 conversions ----------------

__global__ void convert_x_kernel(const float* __restrict__ x, __bf16* __restrict__ xb) {
    int i = blockIdx.x * blockDim.x + threadIdx.x;  // over NN*64/4
    if (i < NN * 16) {
        float4 v = *(const float4*)&x[i * 4];
        xb[i * 4 + 0] = (__bf16)v.x;
        xb[i * 4 + 1] = (__bf16)v.y;
        xb[i * 4 + 2] = (__bf16)v.z;
        xb[i * 4 + 3] = (__bf16)v.w;
    }
}

// w [K][128] fp32 -> wt [128][K] bf16
__global__ void transpose_w_kernel(const float* __restrict__ w, __bf16* __restrict__ wt, int K) {
    int i = blockIdx.x * blockDim.x + threadIdx.x;
    if (i < 128 * K) {
        int n = i / K, k = i % K;
        wt[i] = (__bf16)w[k * 128 + n];
    }
}

// ---------------- gather: agg[n] = in[n] + sum_{j->n} in[j]  (bf16 in/out, fp32 accum) ----------------
// one wave (64 lanes) per node

__global__ void gather64_kernel(const __bf16* __restrict__ in, const int* __restrict__ row_ptr,
                                const int* __restrict__ cols, __bf16* __restrict__ agg) {
    int node = blockIdx.x * (blockDim.x >> 6) + (threadIdx.x >> 6);
    int lane = threadIdx.x & 63;
    if (node >= NN) return;
    int beg = row_ptr[node], end = row_ptr[node + 1];
    float acc = (float)in[(size_t)node * 64 + lane];
    int i = beg;
    for (; i + 4 <= end; i += 4) {
        int c0 = cols[i], c1 = cols[i + 1], c2 = cols[i + 2], c3 = cols[i + 3];
        float v0 = (float)in[(size_t)c0 * 64 + lane];
        float v1 = (float)in[(size_t)c1 * 64 + lane];
        float v2 = (float)in[(size_t)c2 * 64 + lane];
        float v3 = (float)in[(size_t)c3 * 64 + lane];
        acc += (v0 + v1) + (v2 + v3);
    }
    for (; i < end; ++i) acc += (float)in[(size_t)cols[i] * 64 + lane];
    agg[(size_t)node * 64 + lane] = (__bf16)acc;
}

__global__ void gather128_kernel(const __bf16* __restrict__ in, const int* __restrict__ row_ptr,
                                 const int* __restrict__ cols, __bf16* __restrict__ agg) {
    int node = blockIdx.x * (blockDim.x >> 6) + (threadIdx.x >> 6);
    int lane = threadIdx.x & 63;
    if (node >= NN) return;
    const uint32_t* inu = (const uint32_t*)in;
    uint32_t* aggu = (uint32_t*)agg;
    int beg = row_ptr[node], end = row_ptr[node + 1];
    float2 acc = unpack_bf16(inu[(size_t)node * 64 + lane]);
    int i = beg;
    for (; i + 4 <= end; i += 4) {
        int c0 = cols[i], c1 = cols[i + 1], c2 = cols[i + 2], c3 = cols[i + 3];
        uint32_t u0 = inu[(size_t)c0 * 64 + lane];
        uint32_t u1 = inu[(size_t)c1 * 64 + lane];
        uint32_t u2 = inu[(size_t)c2 * 64 + lane];
        uint32_t u3 = inu[(size_t)c3 * 64 + lane];
        float2 v0 = unpack_bf16(u0), v1 = unpack_bf16(u1);
        float2 v2 = unpack_bf16(u2), v3 = unpack_bf16(u3);
        acc.x += (v0.x + v1.x) + (v2.x + v3.x);
        acc.y += (v0.y + v1.y) + (v2.y + v3.y);
    }
    for (; i < end; ++i) {
        float2 v = unpack_bf16(inu[(size_t)cols[i] * 64 + lane]);
        acc.x += v.x; acc.y += v.y;
    }
    aggu[(size_t)node * 64 + lane] = pack_bf16(acc.x, acc.y);
}

// ---------------- fused MLP via MFMA + pooling epilogue ----------------
// out = relu(relu(bn(In@W1+b1))@W2+b2);  p[batch[n], col_off+f] += out[n][f]
// 64 rows x 128 cols per block, 8 waves, mfma_f32_16x16x32_bf16.

template <int K>
__global__ __launch_bounds__(512, 1) void mlp_mfma_kernel(
    const __bf16* __restrict__ agg,   // [NN][K] bf16
    const __bf16* __restrict__ w1t,   // [128][K] bf16 (transposed)
    const float* __restrict__ b1,
    const float* __restrict__ g, const float* __restrict__ be,
    const float* __restrict__ m, const float* __restrict__ v,
    const __bf16* __restrict__ w2t,   // [128][128] bf16 (transposed)
    const float* __restrict__ b2,
    __bf16* __restrict__ out,         // [NN][128] bf16
    const int* __restrict__ batch,    // [NN] sorted graph ids
    float* __restrict__ p,            // [NG][384] pooled accumulator
    int col_off)
{
    constexpr int KP = K + 8;     // pad 8 bf16 (16B): 2-way banks only
    constexpr int KP2 = 136;      // 128 + 8
    __shared__ alignas(16) __bf16 sA[64 * KP];
    __shared__ alignas(16) __bf16 sW1[128 * KP];
    __shared__ alignas(16) __bf16 sW2[128 * KP2];
    __shared__ alignas(16) __bf16 sT[64 * KP2];
    __shared__ alignas(16) __bf16 sOut[64 * KP2];
    __shared__ int sBatch[64];

    int tid = threadIdx.x;
    int wid = tid >> 6, lane = tid & 63;
    int wr = wid >> 1, wc = wid & 1;       // 4 x 2 wave grid
    int l15 = lane & 15, lq = lane >> 4;   // quad 0..3
    int rowbase = blockIdx.x * 64;

    // stage In tile [64][K]
    for (int idx = tid; idx < 64 * (K / 8); idx += 512) {
        int r = idx / (K / 8), kc = idx % (K / 8);
        int n = rowbase + r;
        uint4 val = make_uint4(0, 0, 0, 0);
        if (n < NN) val = *(const uint4*)&agg[(size_t)n * K + kc * 8];
        *(uint4*)&sA[r * KP + kc * 8] = val;
    }
    // stage W1t [128][K]
    for (int idx = tid; idx < 128 * (K / 8); idx += 512) {
        int n = idx / (K / 8), kc = idx % (K / 8);
        *(uint4*)&sW1[n * KP + kc * 8] = *(const uint4*)&w1t[n * K + kc * 8];
    }
    // stage W2t [128][128]
    for (int idx = tid; idx < 128 * 16; idx += 512) {
        int n = idx >> 4, kc = idx & 15;
        *(uint4*)&sW2[n * KP2 + kc * 8] = *(const uint4*)&w2t[n * 128 + kc * 8];
    }
    // stage batch ids for this tile
    if (tid < 64) {
        int n = rowbase + tid;
        sBatch[tid] = (n < NN) ? batch[n] : -1;
    }
    __syncthreads();

    // phase 1: T = relu(bn(In @ W1 + b1))   (wave: 16 rows x 64 cols)
    f32x4 acc[4] = {};
#pragma unroll
    for (int ks = 0; ks < K / 32; ++ks) {
        bf16x8 a = *(const bf16x8*)&sA[(wr * 16 + l15) * KP + ks * 32 + lq * 8];
#pragma unroll
        for (int nf = 0; nf < 4; ++nf) {
            bf16x8 b = *(const bf16x8*)&sW1[(wc * 64 + nf * 16 + l15) * KP + ks * 32 + lq * 8];
            acc[nf] = __builtin_amdgcn_mfma_f32_16x16x32_bf16(a, b, acc[nf], 0, 0, 0);
        }
    }
    // epilogue 1: D[m][n]: n = l15, m = lq*4 + r
#pragma unroll
    for (int nf = 0; nf < 4; ++nf) {
        int c = wc * 64 + nf * 16 + l15;
        float sc = g[c] * rsqrtf(v[c] + BNEPS);
        float sh = be[c] + (b1[c] - m[c]) * sc;
#pragma unroll
        for (int r = 0; r < 4; ++r) {
            int row = wr * 16 + lq * 4 + r;
            float t = fmaxf(acc[nf][r] * sc + sh, 0.f);
            sT[row * KP2 + c] = (__bf16)t;
        }
    }
    __syncthreads();

    // phase 2: out = relu(T @ W2 + b2)
    f32x4 acc2[4] = {};
#pragma unroll
    for (int ks = 0; ks < 4; ++ks) {
        bf16x8 a = *(const bf16x8*)&sT[(wr * 16 + l15) * KP2 + ks * 32 + lq * 8];
#pragma unroll
        for (int nf = 0; nf < 4; ++nf) {
            bf16x8 b = *(const bf16x8*)&sW2[(wc * 64 + nf * 16 + l15) * KP2 + ks * 32 + lq * 8];
            acc2[nf] = __builtin_amdgcn_mfma_f32_16x16x32_bf16(a, b, acc2[nf], 0, 0, 0);
        }
    }
#pragma unroll
    for (int nf = 0; nf < 4; ++nf) {
        int c = wc * 64 + nf * 16 + l15;
        float bb = b2[c];
#pragma unroll
        for (int r = 0; r < 4; ++r) {
            int row = wr * 16 + lq * 4 + r;
            float o = fmaxf(acc2[nf][r] + bb, 0.f);
            sOut[row * KP2 + c] = (__bf16)o;
        }
    }
    __syncthreads();

    // coalesced store
    for (int idx = tid; idx < 64 * 16; idx += 512) {
        int r = idx >> 4, kc = idx & 15;
        int n = rowbase + r;
        if (n < NN)
            *(uint4*)&out[(size_t)n * 128 + kc * 8] = *(const uint4*)&sOut[r * KP2 + kc * 8];
    }

    // fused pooling: 4 row-chunks x 128 features; batch sorted -> run accumulation
    {
        int f = tid & 127;
        int chunk = tid >> 7;          // 0..3, rows chunk*16 .. chunk*16+15
        float pacc = 0.f;
        int cur = -1;
#pragma unroll
        for (int i = 0; i < 16; ++i) {
            int row = chunk * 16 + i;
            int b = sBatch[row];
            if (b < 0) break;          // past NN
            if (b != cur) {
                if (cur >= 0) atomicAdd(&p[cur * 384 + col_off + f], pacc);
                pacc = 0.f;
                cur = b;
            }
            pacc += (float)sOut[row * KP2 + f];
        }
        if (cur >= 0) atomicAdd(&p[cur * 384 + col_off + f], pacc);
    }
}

// ---------------- head: relu(p@lin1+b) @ lin2 + b -> log_softmax ----------------

__global__ __launch_bounds__(384) void head_kernel(const float* __restrict__ p,
                                                   const float* __restrict__ w1,
                                                   const float* __restrict__ b1,
                                                   const float* __restrict__ w2,
                                                   const float* __restrict__ b2,
                                                   float* __restrict__ out) {
    __shared__ float sP[384];
    __shared__ float sH[384];
    __shared__ float sL[10];
    __shared__ float sred[2];
    int gidx = blockIdx.x;
    int t = threadIdx.x;
    sP[t] = p[gidx * 384 + t];
    __syncthreads();
    float acc = b1[t];
#pragma unroll 8
    for (int i = 0; i < 384; ++i) acc += sP[i] * w1[i * 384 + t];
    sH[t] = fmaxf(acc, 0.f);
    __syncthreads();
    if (t < 10) {
        float a2 = b2[t];
#pragma unroll 8
        for (int i = 0; i < 384; ++i) a2 += sH[i] * w2[i * 10 + t];
        sL[t] = a2;
    }
    __syncthreads();
    if (t == 0) {
        float mx = -1e30f;
        for (int c = 0; c < 10; ++c) mx = fmaxf(mx, sL[c]);
        float s = 0.f;
        for (int c = 0; c < 10; ++c) s += expf(sL[c] - mx);
        sred[0] = mx;
        sred[1] = logf(s);
    }
    __syncthreads();
    if (t < 10) out[gidx * 10 + t] = sL[t] - sred[0] - sred[1];
}

// ---------------- launch ----------------

static inline char* align_up(char* ptr, size_t a) {
    return (char*)(((uintptr_t)ptr + a - 1) & ~(uintptr_t)(a - 1));
}

extern "C" void kernel_launch(void* const* d_in, const int* in_sizes, int n_in,
                              void* d_out, int out_size, void* d_ws, size_t ws_size,
                              hipStream_t stream) {
    const float* x = (const float*)d_in[0];
    const int* ei = (const int*)d_in[1];
    const int* batch = (const int*)d_in[2];
    const float* c_w1[3], *c_b1[3], *c_g[3], *c_be[3], *c_m[3], *c_v[3], *c_w2[3], *c_b2[3];
    for (int i = 0; i < 3; ++i) {
        int base = 3 + i * 8;
        c_w1[i] = (const float*)d_in[base + 0];
        c_b1[i] = (const float*)d_in[base + 1];
        c_g[i]  = (const float*)d_in[base + 2];
        c_be[i] = (const float*)d_in[base + 3];
        c_m[i]  = (const float*)d_in[base + 4];
        c_v[i]  = (const float*)d_in[base + 5];
        c_w2[i] = (const float*)d_in[base + 6];
        c_b2[i] = (const float*)d_in[base + 7];
    }
    const float* lin1_w = (const float*)d_in[27];
    const float* lin1_b = (const float*)d_in[28];
    const float* lin2_w = (const float*)d_in[29];
    const float* lin2_b = (const float*)d_in[30];
    const int* src = ei;
    const int* dst = ei + NE;
    float* out = (float*)d_out;

    // workspace carve
    char* ws = (char*)d_ws;
    __bf16* xb  = (__bf16*)ws; ws = align_up(ws + (size_t)NN * 64 * 2, 256);
    __bf16* agg = (__bf16*)ws; ws = align_up(ws + (size_t)NN * 128 * 2, 256);
    __bf16* hA  = (__bf16*)ws; ws = align_up(ws + (size_t)NN * 128 * 2, 256);
    __bf16* hB  = (__bf16*)ws; ws = align_up(ws + (size_t)NN * 128 * 2, 256);
    float* p    = (float*)ws;  ws = align_up(ws + (size_t)NG * 384 * 4, 256);
    int* csr_row = (int*)ws;   ws = align_up(ws + (size_t)(NN + 1) * 4, 256);
    int* cursor  = (int*)ws;   ws = align_up(ws + (size_t)NN * 4, 256);
    int* csr_src = (int*)ws;   ws = align_up(ws + (size_t)NE * 4, 256);
    __bf16* w1t[3]; __bf16* w2t[3];
    for (int i = 0; i < 3; ++i) {
        int K = (i == 0) ? 64 : 128;
        w1t[i] = (__bf16*)ws; ws = align_up(ws + (size_t)128 * K * 2, 256);
        w2t[i] = (__bf16*)ws; ws = align_up(ws + (size_t)128 * 128 * 2, 256);
    }

    // --- prep: CSR build + dtype conversions (per call; deterministic) ---
    hipMemsetAsync(cursor, 0, (size_t)NN * 4, stream);
    degree_kernel<<<(NE + 255) / 256, 256, 0, stream>>>(dst, cursor);
    scan_kernel<<<1, 1024, 0, stream>>>(cursor, csr_row);
    hipMemsetAsync(cursor, 0, (size_t)NN * 4, stream);
    fill_kernel<<<(NE + 255) / 256, 256, 0, stream>>>(src, dst, csr_row, cursor, csr_src);
    hipMemsetAsync(p, 0, (size_t)NG * 384 * 4, stream);

    convert_x_kernel<<<(NN * 16 + 255) / 256, 256, 0, stream>>>(x, xb);
    for (int i = 0; i < 3; ++i) {
        int K = (i == 0) ? 64 : 128;
        transpose_w_kernel<<<(128 * K + 255) / 256, 256, 0, stream>>>(c_w1[i], w1t[i], K);
        transpose_w_kernel<<<(128 * 128 + 255) / 256, 256, 0, stream>>>(c_w2[i], w2t[i], 128);
    }

    const int GATHER_BLOCKS = (NN + 3) / 4;   // 4 waves/block, one wave per node
    const int MLP_BLOCKS = (NN + 63) / 64;

    // layer 1 (K=64)
    gather64_kernel<<<GATHER_BLOCKS, 256, 0, stream>>>(xb, csr_row, csr_src, agg);
    mlp_mfma_kernel<64><<<MLP_BLOCKS, 512, 0, stream>>>(agg, w1t[0], c_b1[0], c_g[0], c_be[0],
                                                        c_m[0], c_v[0], w2t[0], c_b2[0], hA,
                                                        batch, p, 0);

    // layer 2 (K=128)
    gather128_kernel<<<GATHER_BLOCKS, 256, 0, stream>>>(hA, csr_row, csr_src, agg);
    mlp_mfma_kernel<128><<<MLP_BLOCKS, 512, 0, stream>>>(agg, w1t[1], c_b1[1], c_g[1], c_be[1],
                                                         c_m[1], c_v[1], w2t[1], c_b2[1], hB,
                                                         batch, p, 128);

    // layer 3 (K=128)
    gather128_kernel<<<GATHER_BLOCKS, 256, 0, stream>>>(hB, csr_row, csr_src, agg);
    mlp_mfma_kernel<128><<<MLP_BLOCKS, 512, 0, stream>>>(agg, w1t[2], c_b1[2], c_g[2], c_be[2],
                                                         c_m[2], c_v[2], w2t[2], c_b2[2], hA,
                                                         batch, p, 256);

    // head
    head_kernel<<<NG, 384, 0, stream>>>(p, lin1_w, lin1_b, lin2_w, lin2_b, out);
}

// Round 4
// 324.941 us; speedup vs baseline: 2.7073x; 1.2150x over previous
//
#include <hip/hip_runtime.h>
#include <math.h>
#include <stdint.h>

static constexpr int NN = 50000;   // nodes
static constexpr int NE = 800000;  // edges
static constexpr int NG = 512;     // graphs
static constexpr int NB = (NN + 255) / 256;  // 196 scan blocks
static constexpr float BNEPS = 1e-5f;

typedef __bf16 bf16x8 __attribute__((ext_vector_type(8)));
typedef __bf16 bf16x2 __attribute__((ext_vector_type(2)));
typedef float f32x4 __attribute__((ext_vector_type(4)));

__device__ __forceinline__ uint32_t pack_bf16(float x, float y) {
    bf16x2 v; v[0] = (__bf16)x; v[1] = (__bf16)y;
    return __builtin_bit_cast(uint32_t, v);
}
__device__ __forceinline__ float2 unpack_bf16(uint32_t u) {
    bf16x2 v = __builtin_bit_cast(bf16x2, u);
    return make_float2((float)v[0], (float)v[1]);
}

// ---------------- CSR build ----------------

__global__ void degree_kernel(const int* __restrict__ dst, int* __restrict__ deg) {
    int e = blockIdx.x * blockDim.x + threadIdx.x;
    if (e < NE) atomicAdd(&deg[dst[e]], 1);
}

// phase A: per-block (256 nodes) sum of degrees
__global__ __launch_bounds__(256) void blocksum_kernel(const int* __restrict__ deg,
                                                       int* __restrict__ bsum) {
    int i = blockIdx.x * 256 + threadIdx.x;
    int v = (i < NN) ? deg[i] : 0;
#pragma unroll
    for (int off = 32; off; off >>= 1) v += __shfl_down(v, off, 64);
    __shared__ int s[4];
    if ((threadIdx.x & 63) == 0) s[threadIdx.x >> 6] = v;
    __syncthreads();
    if (threadIdx.x == 0) bsum[blockIdx.x] = s[0] + s[1] + s[2] + s[3];
}

// phase B: exclusive scan of NB block sums (single small block)
__global__ __launch_bounds__(256) void scanb_kernel(const int* __restrict__ bsum,
                                                    int* __restrict__ bscan,
                                                    int* __restrict__ row_ptr) {
    __shared__ int s[256];
    int t = threadIdx.x;
    int v = (t < NB) ? bsum[t] : 0;
    s[t] = v;
    __syncthreads();
    for (int off = 1; off < 256; off <<= 1) {
        int u = (t >= off) ? s[t - off] : 0;
        __syncthreads();
        s[t] += u;
        __syncthreads();
    }
    if (t < NB) bscan[t] = s[t] - v;  // exclusive
    if (t == NB - 1) row_ptr[NN] = s[t];
}

// phase C: per-block exclusive scan + global offset -> row_ptr
__global__ __launch_bounds__(256) void scanfinal_kernel(const int* __restrict__ deg,
                                                        const int* __restrict__ bscan,
                                                        int* __restrict__ row_ptr) {
    __shared__ int s[256];
    int t = threadIdx.x;
    int i = blockIdx.x * 256 + t;
    int v = (i < NN) ? deg[i] : 0;
    s[t] = v;
    __syncthreads();
    for (int off = 1; off < 256; off <<= 1) {
        int u = (t >= off) ? s[t - off] : 0;
        __syncthreads();
        s[t] += u;
        __syncthreads();
    }
    if (i < NN) row_ptr[i] = bscan[blockIdx.x] + s[t] - v;
}

__global__ void fill_kernel(const int* __restrict__ src, const int* __restrict__ dst,
                            const int* __restrict__ row_ptr, int* __restrict__ cursor,
                            int* __restrict__ cols) {
    int e = blockIdx.x * blockDim.x + threadIdx.x;
    if (e < NE) {
        int d = dst[e];
        int pos = atomicAdd(&cursor[d], 1);
        cols[row_ptr[d] + pos] = src[e];
    }
}

// ---------------- prep: fp32 -> bf16 conversions ----------------

__global__ void convert_x_kernel(const float* __restrict__ x, __bf16* __restrict__ xb) {
    int i = blockIdx.x * blockDim.x + threadIdx.x;  // over NN*64/4
    if (i < NN * 16) {
        float4 v = *(const float4*)&x[i * 4];
        xb[i * 4 + 0] = (__bf16)v.x;
        xb[i * 4 + 1] = (__bf16)v.y;
        xb[i * 4 + 2] = (__bf16)v.z;
        xb[i * 4 + 3] = (__bf16)v.w;
    }
}

// w [K][128] fp32 -> wt [128][K] bf16
__global__ void transpose_w_kernel(const float* __restrict__ w, __bf16* __restrict__ wt, int K) {
    int i = blockIdx.x * blockDim.x + threadIdx.x;
    if (i < 128 * K) {
        int n = i / K, k = i % K;
        wt[i] = (__bf16)w[k * 128 + n];
    }
}

// ---------------- gather: agg[n] = in[n] + sum_{j->n} in[j]  (bf16 in/out, fp32 accum) ----------------
// one wave (64 lanes) per node

__global__ void gather64_kernel(const __bf16* __restrict__ in, const int* __restrict__ row_ptr,
                                const int* __restrict__ cols, __bf16* __restrict__ agg) {
    int node = blockIdx.x * (blockDim.x >> 6) + (threadIdx.x >> 6);
    int lane = threadIdx.x & 63;
    if (node >= NN) return;
    int beg = row_ptr[node], end = row_ptr[node + 1];
    float acc = (float)in[(size_t)node * 64 + lane];
    int i = beg;
    for (; i + 4 <= end; i += 4) {
        int c0 = cols[i], c1 = cols[i + 1], c2 = cols[i + 2], c3 = cols[i + 3];
        float v0 = (float)in[(size_t)c0 * 64 + lane];
        float v1 = (float)in[(size_t)c1 * 64 + lane];
        float v2 = (float)in[(size_t)c2 * 64 + lane];
        float v3 = (float)in[(size_t)c3 * 64 + lane];
        acc += (v0 + v1) + (v2 + v3);
    }
    for (; i < end; ++i) acc += (float)in[(size_t)cols[i] * 64 + lane];
    agg[(size_t)node * 64 + lane] = (__bf16)acc;
}

__global__ void gather128_kernel(const __bf16* __restrict__ in, const int* __restrict__ row_ptr,
                                 const int* __restrict__ cols, __bf16* __restrict__ agg) {
    int node = blockIdx.x * (blockDim.x >> 6) + (threadIdx.x >> 6);
    int lane = threadIdx.x & 63;
    if (node >= NN) return;
    const uint32_t* inu = (const uint32_t*)in;
    uint32_t* aggu = (uint32_t*)agg;
    int beg = row_ptr[node], end = row_ptr[node + 1];
    float2 acc = unpack_bf16(inu[(size_t)node * 64 + lane]);
    int i = beg;
    for (; i + 4 <= end; i += 4) {
        int c0 = cols[i], c1 = cols[i + 1], c2 = cols[i + 2], c3 = cols[i + 3];
        uint32_t u0 = inu[(size_t)c0 * 64 + lane];
        uint32_t u1 = inu[(size_t)c1 * 64 + lane];
        uint32_t u2 = inu[(size_t)c2 * 64 + lane];
        uint32_t u3 = inu[(size_t)c3 * 64 + lane];
        float2 v0 = unpack_bf16(u0), v1 = unpack_bf16(u1);
        float2 v2 = unpack_bf16(u2), v3 = unpack_bf16(u3);
        acc.x += (v0.x + v1.x) + (v2.x + v3.x);
        acc.y += (v0.y + v1.y) + (v2.y + v3.y);
    }
    for (; i < end; ++i) {
        float2 v = unpack_bf16(inu[(size_t)cols[i] * 64 + lane]);
        acc.x += v.x; acc.y += v.y;
    }
    aggu[(size_t)node * 64 + lane] = pack_bf16(acc.x, acc.y);
}

// ---------------- fused MLP via MFMA + pooling epilogue ----------------
// out = relu(relu(bn(In@W1+b1))@W2+b2);  p[batch[n], col_off+f] += out[n][f]
// 64 rows x 128 cols per block, 8 waves, mfma_f32_16x16x32_bf16.

template <int K, bool WOUT>
__global__ __launch_bounds__(512, 1) void mlp_mfma_kernel(
    const __bf16* __restrict__ agg,   // [NN][K] bf16
    const __bf16* __restrict__ w1t,   // [128][K] bf16 (transposed)
    const float* __restrict__ b1,
    const float* __restrict__ g, const float* __restrict__ be,
    const float* __restrict__ m, const float* __restrict__ v,
    const __bf16* __restrict__ w2t,   // [128][128] bf16 (transposed)
    const float* __restrict__ b2,
    __bf16* __restrict__ out,         // [NN][128] bf16 (unused if !WOUT)
    const int* __restrict__ batch,    // [NN] sorted graph ids
    float* __restrict__ p,            // [NG][384] pooled accumulator
    int col_off)
{
    constexpr int KP = K + 8;     // pad 8 bf16 (16B): 2-way banks only
    constexpr int KP2 = 136;      // 128 + 8
    __shared__ alignas(16) __bf16 sA[64 * KP];
    __shared__ alignas(16) __bf16 sW1[128 * KP];
    __shared__ alignas(16) __bf16 sW2[128 * KP2];
    __shared__ alignas(16) __bf16 sT[64 * KP2];
    __shared__ alignas(16) __bf16 sOut[64 * KP2];
    __shared__ int sBatch[64];

    int tid = threadIdx.x;
    int wid = tid >> 6, lane = tid & 63;
    int wr = wid >> 1, wc = wid & 1;       // 4 x 2 wave grid
    int l15 = lane & 15, lq = lane >> 4;   // quad 0..3
    int rowbase = blockIdx.x * 64;

    // stage In tile [64][K]
    for (int idx = tid; idx < 64 * (K / 8); idx += 512) {
        int r = idx / (K / 8), kc = idx % (K / 8);
        int n = rowbase + r;
        uint4 val = make_uint4(0, 0, 0, 0);
        if (n < NN) val = *(const uint4*)&agg[(size_t)n * K + kc * 8];
        *(uint4*)&sA[r * KP + kc * 8] = val;
    }
    // stage W1t [128][K]
    for (int idx = tid; idx < 128 * (K / 8); idx += 512) {
        int n = idx / (K / 8), kc = idx % (K / 8);
        *(uint4*)&sW1[n * KP + kc * 8] = *(const uint4*)&w1t[n * K + kc * 8];
    }
    // stage W2t [128][128]
    for (int idx = tid; idx < 128 * 16; idx += 512) {
        int n = idx >> 4, kc = idx & 15;
        *(uint4*)&sW2[n * KP2 + kc * 8] = *(const uint4*)&w2t[n * 128 + kc * 8];
    }
    // stage batch ids for this tile
    if (tid < 64) {
        int n = rowbase + tid;
        sBatch[tid] = (n < NN) ? batch[n] : -1;
    }
    __syncthreads();

    // phase 1: T = relu(bn(In @ W1 + b1))   (wave: 16 rows x 64 cols)
    f32x4 acc[4] = {};
#pragma unroll
    for (int ks = 0; ks < K / 32; ++ks) {
        bf16x8 a = *(const bf16x8*)&sA[(wr * 16 + l15) * KP + ks * 32 + lq * 8];
#pragma unroll
        for (int nf = 0; nf < 4; ++nf) {
            bf16x8 b = *(const bf16x8*)&sW1[(wc * 64 + nf * 16 + l15) * KP + ks * 32 + lq * 8];
            acc[nf] = __builtin_amdgcn_mfma_f32_16x16x32_bf16(a, b, acc[nf], 0, 0, 0);
        }
    }
    // epilogue 1: D[m][n]: n = l15, m = lq*4 + r
#pragma unroll
    for (int nf = 0; nf < 4; ++nf) {
        int c = wc * 64 + nf * 16 + l15;
        float sc = g[c] * rsqrtf(v[c] + BNEPS);
        float sh = be[c] + (b1[c] - m[c]) * sc;
#pragma unroll
        for (int r = 0; r < 4; ++r) {
            int row = wr * 16 + lq * 4 + r;
            float t = fmaxf(acc[nf][r] * sc + sh, 0.f);
            sT[row * KP2 + c] = (__bf16)t;
        }
    }
    __syncthreads();

    // phase 2: out = relu(T @ W2 + b2)
    f32x4 acc2[4] = {};
#pragma unroll
    for (int ks = 0; ks < 4; ++ks) {
        bf16x8 a = *(const bf16x8*)&sT[(wr * 16 + l15) * KP2 + ks * 32 + lq * 8];
#pragma unroll
        for (int nf = 0; nf < 4; ++nf) {
            bf16x8 b = *(const bf16x8*)&sW2[(wc * 64 + nf * 16 + l15) * KP2 + ks * 32 + lq * 8];
            acc2[nf] = __builtin_amdgcn_mfma_f32_16x16x32_bf16(a, b, acc2[nf], 0, 0, 0);
        }
    }
#pragma unroll
    for (int nf = 0; nf < 4; ++nf) {
        int c = wc * 64 + nf * 16 + l15;
        float bb = b2[c];
#pragma unroll
        for (int r = 0; r < 4; ++r) {
            int row = wr * 16 + lq * 4 + r;
            float o = fmaxf(acc2[nf][r] + bb, 0.f);
            sOut[row * KP2 + c] = (__bf16)o;
        }
    }
    __syncthreads();

    // coalesced store (skipped for the last layer: pooling is the only consumer)
    if constexpr (WOUT) {
        for (int idx = tid; idx < 64 * 16; idx += 512) {
            int r = idx >> 4, kc = idx & 15;
            int n = rowbase + r;
            if (n < NN)
                *(uint4*)&out[(size_t)n * 128 + kc * 8] = *(const uint4*)&sOut[r * KP2 + kc * 8];
        }
    }

    // fused pooling: 4 row-chunks x 128 features; batch sorted -> run accumulation
    {
        int f = tid & 127;
        int chunk = tid >> 7;          // 0..3, rows chunk*16 .. chunk*16+15
        float pacc = 0.f;
        int cur = -1;
#pragma unroll
        for (int i = 0; i < 16; ++i) {
            int row = chunk * 16 + i;
            int b = sBatch[row];
            if (b < 0) break;          // past NN
            if (b != cur) {
                if (cur >= 0) atomicAdd(&p[cur * 384 + col_off + f], pacc);
                pacc = 0.f;
                cur = b;
            }
            pacc += (float)sOut[row * KP2 + f];
        }
        if (cur >= 0) atomicAdd(&p[cur * 384 + col_off + f], pacc);
    }
}

// ---------------- head: relu(p@lin1+b) @ lin2 + b -> log_softmax ----------------

__global__ __launch_bounds__(384) void head_kernel(const float* __restrict__ p,
                                                   const float* __restrict__ w1,
                                                   const float* __restrict__ b1,
                                                   const float* __restrict__ w2,
                                                   const float* __restrict__ b2,
                                                   float* __restrict__ out) {
    __shared__ float sP[384];
    __shared__ float sH[384];
    __shared__ float sL[10];
    __shared__ float sred[2];
    int gidx = blockIdx.x;
    int t = threadIdx.x;
    sP[t] = p[gidx * 384 + t];
    __syncthreads();
    float acc = b1[t];
#pragma unroll 8
    for (int i = 0; i < 384; ++i) acc += sP[i] * w1[i * 384 + t];
    sH[t] = fmaxf(acc, 0.f);
    __syncthreads();
    if (t < 10) {
        float a2 = b2[t];
#pragma unroll 8
        for (int i = 0; i < 384; ++i) a2 += sH[i] * w2[i * 10 + t];
        sL[t] = a2;
    }
    __syncthreads();
    if (t == 0) {
        float mx = -1e30f;
        for (int c = 0; c < 10; ++c) mx = fmaxf(mx, sL[c]);
        float s = 0.f;
        for (int c = 0; c < 10; ++c) s += expf(sL[c] - mx);
        sred[0] = mx;
        sred[1] = logf(s);
    }
    __syncthreads();
    if (t < 10) out[gidx * 10 + t] = sL[t] - sred[0] - sred[1];
}

// ---------------- launch ----------------

static inline char* align_up(char* ptr, size_t a) {
    return (char*)(((uintptr_t)ptr + a - 1) & ~(uintptr_t)(a - 1));
}

extern "C" void kernel_launch(void* const* d_in, const int* in_sizes, int n_in,
                              void* d_out, int out_size, void* d_ws, size_t ws_size,
                              hipStream_t stream) {
    const float* x = (const float*)d_in[0];
    const int* ei = (const int*)d_in[1];
    const int* batch = (const int*)d_in[2];
    const float* c_w1[3], *c_b1[3], *c_g[3], *c_be[3], *c_m[3], *c_v[3], *c_w2[3], *c_b2[3];
    for (int i = 0; i < 3; ++i) {
        int base = 3 + i * 8;
        c_w1[i] = (const float*)d_in[base + 0];
        c_b1[i] = (const float*)d_in[base + 1];
        c_g[i]  = (const float*)d_in[base + 2];
        c_be[i] = (const float*)d_in[base + 3];
        c_m[i]  = (const float*)d_in[base + 4];
        c_v[i]  = (const float*)d_in[base + 5];
        c_w2[i] = (const float*)d_in[base + 6];
        c_b2[i] = (const float*)d_in[base + 7];
    }
    const float* lin1_w = (const float*)d_in[27];
    const float* lin1_b = (const float*)d_in[28];
    const float* lin2_w = (const float*)d_in[29];
    const float* lin2_b = (const float*)d_in[30];
    const int* src = ei;
    const int* dst = ei + NE;
    float* out = (float*)d_out;

    // workspace carve
    char* ws = (char*)d_ws;
    __bf16* xb  = (__bf16*)ws; ws = align_up(ws + (size_t)NN * 64 * 2, 256);
    __bf16* agg = (__bf16*)ws; ws = align_up(ws + (size_t)NN * 128 * 2, 256);
    __bf16* hA  = (__bf16*)ws; ws = align_up(ws + (size_t)NN * 128 * 2, 256);
    __bf16* hB  = (__bf16*)ws; ws = align_up(ws + (size_t)NN * 128 * 2, 256);
    float* p    = (float*)ws;  ws = align_up(ws + (size_t)NG * 384 * 4, 256);
    int* csr_row = (int*)ws;   ws = align_up(ws + (size_t)(NN + 1) * 4, 256);
    int* cursor  = (int*)ws;   ws = align_up(ws + (size_t)NN * 4, 256);
    int* csr_src = (int*)ws;   ws = align_up(ws + (size_t)NE * 4, 256);
    int* bsum    = (int*)ws;   ws = align_up(ws + (size_t)NB * 4, 256);
    int* bscan   = (int*)ws;   ws = align_up(ws + (size_t)NB * 4, 256);
    __bf16* w1t[3]; __bf16* w2t[3];
    for (int i = 0; i < 3; ++i) {
        int K = (i == 0) ? 64 : 128;
        w1t[i] = (__bf16*)ws; ws = align_up(ws + (size_t)128 * K * 2, 256);
        w2t[i] = (__bf16*)ws; ws = align_up(ws + (size_t)128 * 128 * 2, 256);
    }

    // --- prep: CSR build (parallel scan) + dtype conversions ---
    hipMemsetAsync(cursor, 0, (size_t)NN * 4, stream);
    degree_kernel<<<(NE + 255) / 256, 256, 0, stream>>>(dst, cursor);
    blocksum_kernel<<<NB, 256, 0, stream>>>(cursor, bsum);
    scanb_kernel<<<1, 256, 0, stream>>>(bsum, bscan, csr_row);
    scanfinal_kernel<<<NB, 256, 0, stream>>>(cursor, bscan, csr_row);
    hipMemsetAsync(cursor, 0, (size_t)NN * 4, stream);
    fill_kernel<<<(NE + 255) / 256, 256, 0, stream>>>(src, dst, csr_row, cursor, csr_src);
    hipMemsetAsync(p, 0, (size_t)NG * 384 * 4, stream);

    convert_x_kernel<<<(NN * 16 + 255) / 256, 256, 0, stream>>>(x, xb);
    for (int i = 0; i < 3; ++i) {
        int K = (i == 0) ? 64 : 128;
        transpose_w_kernel<<<(128 * K + 255) / 256, 256, 0, stream>>>(c_w1[i], w1t[i], K);
        transpose_w_kernel<<<(128 * 128 + 255) / 256, 256, 0, stream>>>(c_w2[i], w2t[i], 128);
    }

    const int GATHER_BLOCKS = (NN + 3) / 4;   // 4 waves/block, one wave per node
    const int MLP_BLOCKS = (NN + 63) / 64;

    // layer 1 (K=64)
    gather64_kernel<<<GATHER_BLOCKS, 256, 0, stream>>>(xb, csr_row, csr_src, agg);
    mlp_mfma_kernel<64, true><<<MLP_BLOCKS, 512, 0, stream>>>(agg, w1t[0], c_b1[0], c_g[0], c_be[0],
                                                              c_m[0], c_v[0], w2t[0], c_b2[0], hA,
                                                              batch, p, 0);

    // layer 2 (K=128)
    gather128_kernel<<<GATHER_BLOCKS, 256, 0, stream>>>(hA, csr_row, csr_src, agg);
    mlp_mfma_kernel<128, true><<<MLP_BLOCKS, 512, 0, stream>>>(agg, w1t[1], c_b1[1], c_g[1], c_be[1],
                                                               c_m[1], c_v[1], w2t[1], c_b2[1], hB,
                                                               batch, p, 128);

    // layer 3 (K=128) — output only feeds pooling, skip global store
    gather128_kernel<<<GATHER_BLOCKS, 256, 0, stream>>>(hB, csr_row, csr_src, agg);
    mlp_mfma_kernel<128, false><<<MLP_BLOCKS, 512, 0, stream>>>(agg, w1t[2], c_b1[2], c_g[2], c_be[2],
                                                                c_m[2], c_v[2], w2t[2], c_b2[2], nullptr,
                                                                batch, p, 256);

    // head
    head_kernel<<<NG, 384, 0, stream>>>(p, lin1_w, lin1_b, lin2_w, lin2_b, out);
}

// Round 5
// 269.819 us; speedup vs baseline: 3.2604x; 1.2043x over previous
//
#include <hip/hip_runtime.h>
#include <math.h>
#include <stdint.h>

static constexpr int NN = 50000;   // nodes
static constexpr int NE = 800000;  // edges
static constexpr int NG = 512;     // graphs
static constexpr int NB = (NN + 255) / 256;  // 196 scan blocks
static constexpr float BNEPS = 1e-5f;

typedef __bf16 bf16x8 __attribute__((ext_vector_type(8)));
typedef __bf16 bf16x2 __attribute__((ext_vector_type(2)));
typedef float f32x4 __attribute__((ext_vector_type(4)));

__device__ __forceinline__ uint32_t pack_bf16(float x, float y) {
    bf16x2 v; v[0] = (__bf16)x; v[1] = (__bf16)y;
    return __builtin_bit_cast(uint32_t, v);
}
__device__ __forceinline__ float2 unpack_bf16(uint32_t u) {
    bf16x2 v = __builtin_bit_cast(bf16x2, u);
    return make_float2((float)v[0], (float)v[1]);
}

// ---------------- CSR build ----------------

// degree + per-edge rank in one pass (rank = position within dst's row)
__global__ void degree_kernel(const int* __restrict__ dst, int* __restrict__ deg,
                              int* __restrict__ rank) {
    int e = blockIdx.x * blockDim.x + threadIdx.x;
    if (e < NE) rank[e] = atomicAdd(&deg[dst[e]], 1);
}

// phase A: per-block (256 nodes) sum of degrees
__global__ __launch_bounds__(256) void blocksum_kernel(const int* __restrict__ deg,
                                                       int* __restrict__ bsum) {
    int i = blockIdx.x * 256 + threadIdx.x;
    int v = (i < NN) ? deg[i] : 0;
#pragma unroll
    for (int off = 32; off; off >>= 1) v += __shfl_down(v, off, 64);
    __shared__ int s[4];
    if ((threadIdx.x & 63) == 0) s[threadIdx.x >> 6] = v;
    __syncthreads();
    if (threadIdx.x == 0) bsum[blockIdx.x] = s[0] + s[1] + s[2] + s[3];
}

// phase B: exclusive scan of NB block sums (single small block)
__global__ __launch_bounds__(256) void scanb_kernel(const int* __restrict__ bsum,
                                                    int* __restrict__ bscan,
                                                    int* __restrict__ row_ptr) {
    __shared__ int s[256];
    int t = threadIdx.x;
    int v = (t < NB) ? bsum[t] : 0;
    s[t] = v;
    __syncthreads();
    for (int off = 1; off < 256; off <<= 1) {
        int u = (t >= off) ? s[t - off] : 0;
        __syncthreads();
        s[t] += u;
        __syncthreads();
    }
    if (t < NB) bscan[t] = s[t] - v;  // exclusive
    if (t == NB - 1) row_ptr[NN] = s[t];
}

// phase C: per-block exclusive scan + global offset -> row_ptr
__global__ __launch_bounds__(256) void scanfinal_kernel(const int* __restrict__ deg,
                                                        const int* __restrict__ bscan,
                                                        int* __restrict__ row_ptr) {
    __shared__ int s[256];
    int t = threadIdx.x;
    int i = blockIdx.x * 256 + t;
    int v = (i < NN) ? deg[i] : 0;
    s[t] = v;
    __syncthreads();
    for (int off = 1; off < 256; off <<= 1) {
        int u = (t >= off) ? s[t - off] : 0;
        __syncthreads();
        s[t] += u;
        __syncthreads();
    }
    if (i < NN) row_ptr[i] = bscan[blockIdx.x] + s[t] - v;
}

// atomic-free fill using precomputed rank
__global__ void fill_kernel(const int* __restrict__ src, const int* __restrict__ dst,
                            const int* __restrict__ row_ptr, const int* __restrict__ rank,
                            int* __restrict__ cols) {
    int e = blockIdx.x * blockDim.x + threadIdx.x;
    if (e < NE) cols[row_ptr[dst[e]] + rank[e]] = src[e];
}

// ---------------- prep: fp32 -> bf16 conversions ----------------

__global__ void convert_x_kernel(const float* __restrict__ x, __bf16* __restrict__ xb) {
    int i = blockIdx.x * blockDim.x + threadIdx.x;  // over NN*64/4
    if (i < NN * 16) {
        float4 v = *(const float4*)&x[i * 4];
        xb[i * 4 + 0] = (__bf16)v.x;
        xb[i * 4 + 1] = (__bf16)v.y;
        xb[i * 4 + 2] = (__bf16)v.z;
        xb[i * 4 + 3] = (__bf16)v.w;
    }
}

// one kernel: transpose+convert all weights to bf16 [n][k]
// segs: 0: w1[0] K=64; 1,2: w1[1..2] K=128; 3..5: w2[0..2] K=128; 6: lin1 K=384
__global__ void prep_w_kernel(const float* s0, const float* s1, const float* s2,
                              const float* s3, const float* s4, const float* s5,
                              const float* s6,
                              __bf16* d0, __bf16* d1, __bf16* d2,
                              __bf16* d3, __bf16* d4, __bf16* d5, __bf16* d6) {
    int i = blockIdx.x * blockDim.x + threadIdx.x;
    if (i < 8192) {
        int l = i;           int n = l / 64,  k = l % 64;  d0[l] = (__bf16)s0[k * 128 + n];
    } else if (i < 24576) {
        int l = i - 8192;    int n = l / 128, k = l % 128; d1[l] = (__bf16)s1[k * 128 + n];
    } else if (i < 40960) {
        int l = i - 24576;   int n = l / 128, k = l % 128; d2[l] = (__bf16)s2[k * 128 + n];
    } else if (i < 57344) {
        int l = i - 40960;   int n = l / 128, k = l % 128; d3[l] = (__bf16)s3[k * 128 + n];
    } else if (i < 73728) {
        int l = i - 57344;   int n = l / 128, k = l % 128; d4[l] = (__bf16)s4[k * 128 + n];
    } else if (i < 90112) {
        int l = i - 73728;   int n = l / 128, k = l % 128; d5[l] = (__bf16)s5[k * 128 + n];
    } else if (i < 237568) {
        int l = i - 90112;   int n = l / 384, k = l % 384; d6[l] = (__bf16)s6[k * 384 + n];
    }
}

// ---------------- gather: agg[n] = in[n] + sum_{j->n} in[j]  (bf16 in/out, fp32 accum) ----------------
// one wave (64 lanes) per node

__global__ void gather64_kernel(const __bf16* __restrict__ in, const int* __restrict__ row_ptr,
                                const int* __restrict__ cols, __bf16* __restrict__ agg) {
    int node = blockIdx.x * (blockDim.x >> 6) + (threadIdx.x >> 6);
    int lane = threadIdx.x & 63;
    if (node >= NN) return;
    int beg = row_ptr[node], end = row_ptr[node + 1];
    float acc = (float)in[(size_t)node * 64 + lane];
    int i = beg;
    for (; i + 4 <= end; i += 4) {
        int c0 = cols[i], c1 = cols[i + 1], c2 = cols[i + 2], c3 = cols[i + 3];
        float v0 = (float)in[(size_t)c0 * 64 + lane];
        float v1 = (float)in[(size_t)c1 * 64 + lane];
        float v2 = (float)in[(size_t)c2 * 64 + lane];
        float v3 = (float)in[(size_t)c3 * 64 + lane];
        acc += (v0 + v1) + (v2 + v3);
    }
    for (; i < end; ++i) acc += (float)in[(size_t)cols[i] * 64 + lane];
    agg[(size_t)node * 64 + lane] = (__bf16)acc;
}

__global__ void gather128_kernel(const __bf16* __restrict__ in, const int* __restrict__ row_ptr,
                                 const int* __restrict__ cols, __bf16* __restrict__ agg) {
    int node = blockIdx.x * (blockDim.x >> 6) + (threadIdx.x >> 6);
    int lane = threadIdx.x & 63;
    if (node >= NN) return;
    const uint32_t* inu = (const uint32_t*)in;
    uint32_t* aggu = (uint32_t*)agg;
    int beg = row_ptr[node], end = row_ptr[node + 1];
    float2 acc = unpack_bf16(inu[(size_t)node * 64 + lane]);
    int i = beg;
    for (; i + 4 <= end; i += 4) {
        int c0 = cols[i], c1 = cols[i + 1], c2 = cols[i + 2], c3 = cols[i + 3];
        uint32_t u0 = inu[(size_t)c0 * 64 + lane];
        uint32_t u1 = inu[(size_t)c1 * 64 + lane];
        uint32_t u2 = inu[(size_t)c2 * 64 + lane];
        uint32_t u3 = inu[(size_t)c3 * 64 + lane];
        float2 v0 = unpack_bf16(u0), v1 = unpack_bf16(u1);
        float2 v2 = unpack_bf16(u2), v3 = unpack_bf16(u3);
        acc.x += (v0.x + v1.x) + (v2.x + v3.x);
        acc.y += (v0.y + v1.y) + (v2.y + v3.y);
    }
    for (; i < end; ++i) {
        float2 v = unpack_bf16(inu[(size_t)cols[i] * 64 + lane]);
        acc.x += v.x; acc.y += v.y;
    }
    aggu[(size_t)node * 64 + lane] = pack_bf16(acc.x, acc.y);
}

// ---------------- fused MLP via MFMA + pooling epilogue ----------------

template <int K, bool WOUT>
__global__ __launch_bounds__(512, 1) void mlp_mfma_kernel(
    const __bf16* __restrict__ agg,   // [NN][K] bf16
    const __bf16* __restrict__ w1t,   // [128][K] bf16 (transposed)
    const float* __restrict__ b1,
    const float* __restrict__ g, const float* __restrict__ be,
    const float* __restrict__ m, const float* __restrict__ v,
    const __bf16* __restrict__ w2t,   // [128][128] bf16 (transposed)
    const float* __restrict__ b2,
    __bf16* __restrict__ out,         // [NN][128] bf16 (unused if !WOUT)
    const int* __restrict__ batch,    // [NN] sorted graph ids
    float* __restrict__ p,            // [NG][384] pooled accumulator
    int col_off)
{
    constexpr int KP = K + 8;
    constexpr int KP2 = 136;
    __shared__ alignas(16) __bf16 sA[64 * KP];
    __shared__ alignas(16) __bf16 sW1[128 * KP];
    __shared__ alignas(16) __bf16 sW2[128 * KP2];
    __shared__ alignas(16) __bf16 sT[64 * KP2];
    __shared__ alignas(16) __bf16 sOut[64 * KP2];
    __shared__ int sBatch[64];

    int tid = threadIdx.x;
    int wid = tid >> 6, lane = tid & 63;
    int wr = wid >> 1, wc = wid & 1;
    int l15 = lane & 15, lq = lane >> 4;
    int rowbase = blockIdx.x * 64;

    for (int idx = tid; idx < 64 * (K / 8); idx += 512) {
        int r = idx / (K / 8), kc = idx % (K / 8);
        int n = rowbase + r;
        uint4 val = make_uint4(0, 0, 0, 0);
        if (n < NN) val = *(const uint4*)&agg[(size_t)n * K + kc * 8];
        *(uint4*)&sA[r * KP + kc * 8] = val;
    }
    for (int idx = tid; idx < 128 * (K / 8); idx += 512) {
        int n = idx / (K / 8), kc = idx % (K / 8);
        *(uint4*)&sW1[n * KP + kc * 8] = *(const uint4*)&w1t[n * K + kc * 8];
    }
    for (int idx = tid; idx < 128 * 16; idx += 512) {
        int n = idx >> 4, kc = idx & 15;
        *(uint4*)&sW2[n * KP2 + kc * 8] = *(const uint4*)&w2t[n * 128 + kc * 8];
    }
    if (tid < 64) {
        int n = rowbase + tid;
        sBatch[tid] = (n < NN) ? batch[n] : -1;
    }
    __syncthreads();

    f32x4 acc[4] = {};
#pragma unroll
    for (int ks = 0; ks < K / 32; ++ks) {
        bf16x8 a = *(const bf16x8*)&sA[(wr * 16 + l15) * KP + ks * 32 + lq * 8];
#pragma unroll
        for (int nf = 0; nf < 4; ++nf) {
            bf16x8 b = *(const bf16x8*)&sW1[(wc * 64 + nf * 16 + l15) * KP + ks * 32 + lq * 8];
            acc[nf] = __builtin_amdgcn_mfma_f32_16x16x32_bf16(a, b, acc[nf], 0, 0, 0);
        }
    }
#pragma unroll
    for (int nf = 0; nf < 4; ++nf) {
        int c = wc * 64 + nf * 16 + l15;
        float sc = g[c] * rsqrtf(v[c] + BNEPS);
        float sh = be[c] + (b1[c] - m[c]) * sc;
#pragma unroll
        for (int r = 0; r < 4; ++r) {
            int row = wr * 16 + lq * 4 + r;
            float t = fmaxf(acc[nf][r] * sc + sh, 0.f);
            sT[row * KP2 + c] = (__bf16)t;
        }
    }
    __syncthreads();

    f32x4 acc2[4] = {};
#pragma unroll
    for (int ks = 0; ks < 4; ++ks) {
        bf16x8 a = *(const bf16x8*)&sT[(wr * 16 + l15) * KP2 + ks * 32 + lq * 8];
#pragma unroll
        for (int nf = 0; nf < 4; ++nf) {
            bf16x8 b = *(const bf16x8*)&sW2[(wc * 64 + nf * 16 + l15) * KP2 + ks * 32 + lq * 8];
            acc2[nf] = __builtin_amdgcn_mfma_f32_16x16x32_bf16(a, b, acc2[nf], 0, 0, 0);
        }
    }
#pragma unroll
    for (int nf = 0; nf < 4; ++nf) {
        int c = wc * 64 + nf * 16 + l15;
        float bb = b2[c];
#pragma unroll
        for (int r = 0; r < 4; ++r) {
            int row = wr * 16 + lq * 4 + r;
            float o = fmaxf(acc2[nf][r] + bb, 0.f);
            sOut[row * KP2 + c] = (__bf16)o;
        }
    }
    __syncthreads();

    if constexpr (WOUT) {
        for (int idx = tid; idx < 64 * 16; idx += 512) {
            int r = idx >> 4, kc = idx & 15;
            int n = rowbase + r;
            if (n < NN)
                *(uint4*)&out[(size_t)n * 128 + kc * 8] = *(const uint4*)&sOut[r * KP2 + kc * 8];
        }
    }

    {
        int f = tid & 127;
        int chunk = tid >> 7;
        float pacc = 0.f;
        int cur = -1;
#pragma unroll
        for (int i = 0; i < 16; ++i) {
            int row = chunk * 16 + i;
            int b = sBatch[row];
            if (b < 0) break;
            if (b != cur) {
                if (cur >= 0) atomicAdd(&p[cur * 384 + col_off + f], pacc);
                pacc = 0.f;
                cur = b;
            }
            pacc += (float)sOut[row * KP2 + f];
        }
        if (cur >= 0) atomicAdd(&p[cur * 384 + col_off + f], pacc);
    }
}

// ---------------- head stage 1: hrelu = relu(p @ lin1 + b)  via MFMA ----------------
// p [512][384] fp32 (converted inline), lin1t [384][384] bf16. grid (8, 3), 512 thr.

__global__ __launch_bounds__(512, 1) void head1_kernel(const float* __restrict__ p,
                                                       const __bf16* __restrict__ lin1t,
                                                       const float* __restrict__ b1,
                                                       float* __restrict__ hrelu) {
    constexpr int KPA = 392;   // 384 + 8
    constexpr int KPW = 136;   // 128 + 8
    __shared__ alignas(16) __bf16 sA[64 * KPA];
    __shared__ alignas(16) __bf16 sW[128 * KPW];

    int tid = threadIdx.x;
    int wid = tid >> 6, lane = tid & 63;
    int wr = wid >> 1, wc = wid & 1;
    int l15 = lane & 15, lq = lane >> 4;
    int rowbase = blockIdx.x * 64;     // 0..448
    int colbase = blockIdx.y * 128;    // 0, 128, 256

    // stage A: p rows fp32 -> bf16, 64 x 384
    for (int idx = tid; idx < 64 * 48; idx += 512) {
        int r = idx / 48, kc = idx % 48;
        const float* srcp = &p[(rowbase + r) * 384 + kc * 8];
        float4 v0 = *(const float4*)srcp;
        float4 v1 = *(const float4*)(srcp + 4);
        bf16x8 o;
        o[0] = (__bf16)v0.x; o[1] = (__bf16)v0.y; o[2] = (__bf16)v0.z; o[3] = (__bf16)v0.w;
        o[4] = (__bf16)v1.x; o[5] = (__bf16)v1.y; o[6] = (__bf16)v1.z; o[7] = (__bf16)v1.w;
        *(bf16x8*)&sA[r * KPA + kc * 8] = o;
    }

    f32x4 acc[4] = {};
#pragma unroll
    for (int kchunk = 0; kchunk < 3; ++kchunk) {
        for (int idx = tid; idx < 128 * 16; idx += 512) {
            int n = idx >> 4, kc = idx & 15;
            *(uint4*)&sW[n * KPW + kc * 8] =
                *(const uint4*)&lin1t[(colbase + n) * 384 + kchunk * 128 + kc * 8];
        }
        __syncthreads();
#pragma unroll
        for (int ks = 0; ks < 4; ++ks) {
            bf16x8 a = *(const bf16x8*)&sA[(wr * 16 + l15) * KPA + kchunk * 128 + ks * 32 + lq * 8];
#pragma unroll
            for (int nf = 0; nf < 4; ++nf) {
                bf16x8 b = *(const bf16x8*)&sW[(wc * 64 + nf * 16 + l15) * KPW + ks * 32 + lq * 8];
                acc[nf] = __builtin_amdgcn_mfma_f32_16x16x32_bf16(a, b, acc[nf], 0, 0, 0);
            }
        }
        __syncthreads();
    }
#pragma unroll
    for (int nf = 0; nf < 4; ++nf) {
        int col = colbase + wc * 64 + nf * 16 + l15;
        float bb = b1[col];
#pragma unroll
        for (int r = 0; r < 4; ++r) {
            int row = rowbase + wr * 16 + lq * 4 + r;
            hrelu[row * 384 + col] = fmaxf(acc[nf][r] + bb, 0.f);
        }
    }
}

// ---------------- head stage 2: logits + log_softmax, one wave per graph ----------------

__global__ __launch_bounds__(256) void head2_kernel(const float* __restrict__ hrelu,
                                                    const float* __restrict__ w2,   // [384][10]
                                                    const float* __restrict__ b2,
                                                    float* __restrict__ out) {
    int wid = threadIdx.x >> 6, lane = threadIdx.x & 63;
    int gidx = blockIdx.x * 4 + wid;   // grid 128 -> 512 graphs
    const float* hr = &hrelu[gidx * 384 + lane * 6];
    float h[6];
#pragma unroll
    for (int u = 0; u < 6; ++u) h[u] = hr[u];
    float logit[10];
#pragma unroll
    for (int c = 0; c < 10; ++c) {
        float s = 0.f;
#pragma unroll
        for (int u = 0; u < 6; ++u) s = fmaf(h[u], w2[(lane * 6 + u) * 10 + c], s);
#pragma unroll
        for (int off = 32; off; off >>= 1) s += __shfl_xor(s, off, 64);
        logit[c] = s + b2[c];
    }
    float mx = logit[0];
#pragma unroll
    for (int c = 1; c < 10; ++c) mx = fmaxf(mx, logit[c]);
    float se = 0.f;
#pragma unroll
    for (int c = 0; c < 10; ++c) se += expf(logit[c] - mx);
    float lse = logf(se);
    float val = 0.f;
#pragma unroll
    for (int c = 0; c < 10; ++c) if (lane == c) val = logit[c];
    if (lane < 10) out[gidx * 10 + lane] = val - mx - lse;
}

// ---------------- launch ----------------

static inline char* align_up(char* ptr, size_t a) {
    return (char*)(((uintptr_t)ptr + a - 1) & ~(uintptr_t)(a - 1));
}

extern "C" void kernel_launch(void* const* d_in, const int* in_sizes, int n_in,
                              void* d_out, int out_size, void* d_ws, size_t ws_size,
                              hipStream_t stream) {
    const float* x = (const float*)d_in[0];
    const int* ei = (const int*)d_in[1];
    const int* batch = (const int*)d_in[2];
    const float* c_w1[3], *c_b1[3], *c_g[3], *c_be[3], *c_m[3], *c_v[3], *c_w2[3], *c_b2[3];
    for (int i = 0; i < 3; ++i) {
        int base = 3 + i * 8;
        c_w1[i] = (const float*)d_in[base + 0];
        c_b1[i] = (const float*)d_in[base + 1];
        c_g[i]  = (const float*)d_in[base + 2];
        c_be[i] = (const float*)d_in[base + 3];
        c_m[i]  = (const float*)d_in[base + 4];
        c_v[i]  = (const float*)d_in[base + 5];
        c_w2[i] = (const float*)d_in[base + 6];
        c_b2[i] = (const float*)d_in[base + 7];
    }
    const float* lin1_w = (const float*)d_in[27];
    const float* lin1_b = (const float*)d_in[28];
    const float* lin2_w = (const float*)d_in[29];
    const float* lin2_b = (const float*)d_in[30];
    const int* src = ei;
    const int* dst = ei + NE;
    float* out = (float*)d_out;

    // workspace carve
    char* ws = (char*)d_ws;
    __bf16* xb  = (__bf16*)ws; ws = align_up(ws + (size_t)NN * 64 * 2, 256);
    __bf16* agg = (__bf16*)ws; ws = align_up(ws + (size_t)NN * 128 * 2, 256);
    __bf16* hA  = (__bf16*)ws; ws = align_up(ws + (size_t)NN * 128 * 2, 256);
    __bf16* hB  = (__bf16*)ws; ws = align_up(ws + (size_t)NN * 128 * 2, 256);
    float* p    = (float*)ws;  ws = align_up(ws + (size_t)NG * 384 * 4, 256);
    float* hrelu = (float*)ws; ws = align_up(ws + (size_t)NG * 384 * 4, 256);
    int* csr_row = (int*)ws;   ws = align_up(ws + (size_t)(NN + 1) * 4, 256);
    int* cursor  = (int*)ws;   ws = align_up(ws + (size_t)NN * 4, 256);
    int* csr_src = (int*)ws;   ws = align_up(ws + (size_t)NE * 4, 256);
    int* rank    = (int*)ws;   ws = align_up(ws + (size_t)NE * 4, 256);
    int* bsum    = (int*)ws;   ws = align_up(ws + (size_t)NB * 4, 256);
    int* bscan   = (int*)ws;   ws = align_up(ws + (size_t)NB * 4, 256);
    __bf16* w1t[3]; __bf16* w2t[3];
    for (int i = 0; i < 3; ++i) {
        int K = (i == 0) ? 64 : 128;
        w1t[i] = (__bf16*)ws; ws = align_up(ws + (size_t)128 * K * 2, 256);
        w2t[i] = (__bf16*)ws; ws = align_up(ws + (size_t)128 * 128 * 2, 256);
    }
    __bf16* lin1t = (__bf16*)ws; ws = align_up(ws + (size_t)384 * 384 * 2, 256);

    // --- prep: CSR build (single-atomic-pass) + dtype conversions ---
    hipMemsetAsync(cursor, 0, (size_t)NN * 4, stream);
    degree_kernel<<<(NE + 255) / 256, 256, 0, stream>>>(dst, cursor, rank);
    blocksum_kernel<<<NB, 256, 0, stream>>>(cursor, bsum);
    scanb_kernel<<<1, 256, 0, stream>>>(bsum, bscan, csr_row);
    scanfinal_kernel<<<NB, 256, 0, stream>>>(cursor, bscan, csr_row);
    fill_kernel<<<(NE + 255) / 256, 256, 0, stream>>>(src, dst, csr_row, rank, csr_src);
    hipMemsetAsync(p, 0, (size_t)NG * 384 * 4, stream);

    convert_x_kernel<<<(NN * 16 + 255) / 256, 256, 0, stream>>>(x, xb);
    prep_w_kernel<<<(237568 + 255) / 256, 256, 0, stream>>>(
        c_w1[0], c_w1[1], c_w1[2], c_w2[0], c_w2[1], c_w2[2], lin1_w,
        w1t[0], w1t[1], w1t[2], w2t[0], w2t[1], w2t[2], lin1t);

    const int GATHER_BLOCKS = (NN + 3) / 4;
    const int MLP_BLOCKS = (NN + 63) / 64;

    // layer 1 (K=64)
    gather64_kernel<<<GATHER_BLOCKS, 256, 0, stream>>>(xb, csr_row, csr_src, agg);
    mlp_mfma_kernel<64, true><<<MLP_BLOCKS, 512, 0, stream>>>(agg, w1t[0], c_b1[0], c_g[0], c_be[0],
                                                              c_m[0], c_v[0], w2t[0], c_b2[0], hA,
                                                              batch, p, 0);

    // layer 2 (K=128)
    gather128_kernel<<<GATHER_BLOCKS, 256, 0, stream>>>(hA, csr_row, csr_src, agg);
    mlp_mfma_kernel<128, true><<<MLP_BLOCKS, 512, 0, stream>>>(agg, w1t[1], c_b1[1], c_g[1], c_be[1],
                                                               c_m[1], c_v[1], w2t[1], c_b2[1], hB,
                                                               batch, p, 128);

    // layer 3 (K=128) — output only feeds pooling
    gather128_kernel<<<GATHER_BLOCKS, 256, 0, stream>>>(hB, csr_row, csr_src, agg);
    mlp_mfma_kernel<128, false><<<MLP_BLOCKS, 512, 0, stream>>>(agg, w1t[2], c_b1[2], c_g[2], c_be[2],
                                                                c_m[2], c_v[2], w2t[2], c_b2[2], nullptr,
                                                                batch, p, 256);

    // head: MFMA GEMM + per-wave logits/log_softmax
    head1_kernel<<<dim3(8, 3), 512, 0, stream>>>(p, lin1t, lin1_b, hrelu);
    head2_kernel<<<128, 256, 0, stream>>>(hrelu, lin2_w, lin2_b, out);
}